// Round 8
// baseline (691.730 us; speedup 1.0000x reference)
//
#include <hip/hip_runtime.h>
#include <cmath>

#define L_SEQ 2048
#define BATCH 8
#define CIN 256
#define DIN 512
#define M_ROWS (BATCH * L_SEQ)  // 16384
#define NC 64                   // scan chunks
#define LC 32                   // chunk length

typedef __attribute__((ext_vector_type(8))) short short8;
typedef __attribute__((ext_vector_type(2))) unsigned short ushort2v;
typedef __attribute__((ext_vector_type(4))) float float4v;
typedef __attribute__((ext_vector_type(2))) float float2v;
typedef unsigned short u16;

__device__ inline u16 f2bf_rn(float x) {
  union { float f; unsigned u; } v;
  v.f = x;
  unsigned r = v.u + 0x7FFF + ((v.u >> 16) & 1);
  return (u16)(r >> 16);
}
__device__ inline float bf2f(u16 h) {
  union { unsigned u; float f; } v;
  v.u = ((unsigned)h) << 16;
  return v.f;
}

// async 16B global->LDS (gfx950). LDS dest = wave-uniform base + lane*16.
__device__ inline void gl_lds16(const u16* g, u16* l) {
  __builtin_amdgcn_global_load_lds(
      (const __attribute__((address_space(1))) unsigned int*)(const void*)g,
      (__attribute__((address_space(3))) unsigned int*)(void*)l, 16, 0, 0);
}

// ---------------- transpose (B,C,L) -> (B,L,C), hi/lo bf16 planes ----------------
__global__ __launch_bounds__(256) void transpose_in(const float* __restrict__ in,
                                                    u16* __restrict__ xh, u16* __restrict__ xl) {
  __shared__ float tile[32][33];
  int b = blockIdx.z;
  int l0 = blockIdx.x * 32, c0 = blockIdx.y * 32;
  int tx = threadIdx.x, ty = threadIdx.y;  // 32 x 8
#pragma unroll
  for (int k = 0; k < 4; ++k)
    tile[ty + k * 8][tx] = in[(long)(b * CIN + c0 + ty + k * 8) * L_SEQ + l0 + tx];
  __syncthreads();
#pragma unroll
  for (int k = 0; k < 4; ++k) {
    float v = tile[tx][ty + k * 8];
    long o = (long)(b * L_SEQ + l0 + ty + k * 8) * CIN + c0 + tx;
    u16 h = f2bf_rn(v);
    xh[o] = h;
    xl[o] = f2bf_rn(v - bf2f(h));
  }
}

// ---------------- weight packing to planes ----------------
__global__ __launch_bounds__(256) void split_pack(const float* __restrict__ in,
                                                  u16* __restrict__ oh, u16* __restrict__ ol,
                                                  int n) {
  int i = blockIdx.x * 256 + threadIdx.x;
  if (i < n) {
    float v = in[i];
    u16 h = f2bf_rn(v);
    oh[i] = h;
    ol[i] = f2bf_rn(v - bf2f(h));
  }
}

// Wd (640 x 512): rows 0..511 = dt_proj_w @ x_proj_w[0:16]; 512..543 = B,C rows; rest 0
__global__ __launch_bounds__(256) void build_wd(const float* __restrict__ xpw,
                                                const float* __restrict__ dtw,
                                                u16* __restrict__ Wh, u16* __restrict__ Wl) {
  int k = blockIdx.x * 256 + threadIdx.x;  // 0..511
  int n = blockIdx.y;                      // 0..639
  float v;
  if (n < 512) {
    v = 0.f;
#pragma unroll
    for (int r = 0; r < 16; ++r) v += dtw[n * 16 + r] * xpw[r * 512 + k];
  } else if (n < 544) {
    v = xpw[(16 + n - 512) * 512 + k];
  } else {
    v = 0.f;
  }
  u16 h = f2bf_rn(v);
  Wh[(long)n * 512 + k] = h;
  Wl[(long)n * 512 + k] = f2bf_rn(v - bf2f(h));
}

// W_comb (512 x 512): out_lin_w (512x256) @ out_proj_w[layer1] (256x512)
__global__ __launch_bounds__(256) void build_wcomb(const float* __restrict__ olw,
                                                   const float* __restrict__ opw,
                                                   u16* __restrict__ Wh, u16* __restrict__ Wl) {
  int d = blockIdx.x * 256 + threadIdx.x;  // 0..511
  int o = blockIdx.y;                      // 0..511
  float v = 0.f;
#pragma unroll 4
  for (int c = 0; c < 256; ++c) v += olw[o * 256 + c] * opw[(long)c * 512 + d];
  u16 h = f2bf_rn(v);
  Wh[(long)o * 512 + d] = h;
  Wl[(long)o * 512 + d] = f2bf_rn(v - bf2f(h));
}

// ---------------- bf16x3 MFMA GEMM, async global->LDS staging ----------------
// C[m,n] = sum_k A[m,k]*W[n,k]; acc += AhWh + AlWh + AhWl.
// Staging: global_load_lds width=16, unpadded LDS rows of 32 halfs (64 B).
// EPI 2: relu(v+bias[n]) scatter to (spk,b,c,l) fp32 (final).
// EPI 3: split fp32 store: n<512 -> C (xr, stride 512); else C2 (z, stride 512).
// EPI 4: n<512: softplus(v+bias[n]) -> C (delta, 512); 512<=n<544 -> C2 (bc, 32); else skip.
// EPI 5: hi/lo plane store -> Ch/Cl (stride 256).
template <int EPI>
__global__ __launch_bounds__(256) void gemm_mfma(const u16* __restrict__ Ahp,
                                                 const u16* __restrict__ Alp, int lda,
                                                 const u16* __restrict__ Whp,
                                                 const u16* __restrict__ Wlp, int K,
                                                 float* __restrict__ C, float* __restrict__ C2,
                                                 u16* __restrict__ Ch, u16* __restrict__ Cl,
                                                 const float* __restrict__ bias) {
  __shared__ u16 Ah[128 * 32], Al[128 * 32];
  __shared__ u16 Wh[128 * 32], Wl[128 * 32];
  int tid = threadIdx.x;
  int w = tid >> 6, L = tid & 63;
  int q = L >> 4, r16 = L & 15;
  int wm = (w >> 1) * 64, wn = (w & 1) * 64;
  long m0 = (long)blockIdx.y * 128, n0 = (long)blockIdx.x * 128;
  float4v acc[4][4];
#pragma unroll
  for (int i = 0; i < 4; ++i)
#pragma unroll
    for (int j = 0; j < 4; ++j) acc[i][j] = (float4v){0.f, 0.f, 0.f, 0.f};

  int lrow = L >> 2;        // row within 16-row chunk
  int lcol = (L & 3) * 8;   // half-offset within 64 B row

  for (int k0 = 0; k0 < K; k0 += 32) {
    // 8 chunks of 1024 B per array; wave w stages chunks {w, w+4} of each array
#pragma unroll
    for (int is = 0; is < 2; ++is) {
      int chunk = w + is * 4;
      int row = chunk * 16 + lrow;
      long ga = (m0 + row) * (long)lda + k0 + lcol;
      long gw = (n0 + row) * (long)K + k0 + lcol;
      u16* lbase = (u16*)0;  // per-array below (wave-uniform offsets)
      gl_lds16(&Ahp[ga], &Ah[chunk * 512]);
      gl_lds16(&Alp[ga], &Al[chunk * 512]);
      gl_lds16(&Whp[gw], &Wh[chunk * 512]);
      gl_lds16(&Wlp[gw], &Wl[chunk * 512]);
      (void)lbase;
    }
    __syncthreads();
    short8 ah[4], al[4], bh[4], bl[4];
#pragma unroll
    for (int i = 0; i < 4; ++i) {
      int mr = wm + i * 16 + r16;
      ah[i] = *(const short8*)&Ah[mr * 32 + q * 8];
      al[i] = *(const short8*)&Al[mr * 32 + q * 8];
    }
#pragma unroll
    for (int j = 0; j < 4; ++j) {
      int nr = wn + j * 16 + r16;
      bh[j] = *(const short8*)&Wh[nr * 32 + q * 8];
      bl[j] = *(const short8*)&Wl[nr * 32 + q * 8];
    }
#pragma unroll
    for (int i = 0; i < 4; ++i)
#pragma unroll
      for (int j = 0; j < 4; ++j) {
        acc[i][j] = __builtin_amdgcn_mfma_f32_16x16x32_bf16(ah[i], bh[j], acc[i][j], 0, 0, 0);
        acc[i][j] = __builtin_amdgcn_mfma_f32_16x16x32_bf16(al[i], bh[j], acc[i][j], 0, 0, 0);
        acc[i][j] = __builtin_amdgcn_mfma_f32_16x16x32_bf16(ah[i], bl[j], acc[i][j], 0, 0, 0);
      }
    __syncthreads();
  }

  // D layout (16x16x32): row = q*4 + r, col = r16
#pragma unroll
  for (int i = 0; i < 4; ++i) {
    int m = (int)m0 + wm + i * 16 + q * 4;
#pragma unroll
    for (int j = 0; j < 4; ++j) {
      int n = (int)n0 + wn + j * 16 + r16;
      if (EPI == 3) {
        float* dst = (n < 512) ? C : C2;
        int nn = n & 511;
#pragma unroll
        for (int r = 0; r < 4; ++r) dst[(long)(m + r) * 512 + nn] = acc[i][j][r];
      } else if (EPI == 4) {
        if (n < 512) {
          float vb = bias[n];
#pragma unroll
          for (int r = 0; r < 4; ++r) {
            float t = acc[i][j][r] + vb;
            t = (t > 20.f) ? t : __logf(1.f + __expf(t));
            C[(long)(m + r) * 512 + n] = t;
          }
        } else if (n < 544) {
#pragma unroll
          for (int r = 0; r < 4; ++r) C2[(long)(m + r) * 32 + (n - 512)] = acc[i][j][r];
        }
      } else if (EPI == 5) {
#pragma unroll
        for (int r = 0; r < 4; ++r) {
          float v = acc[i][j][r];
          u16 h = f2bf_rn(v);
          Ch[(long)(m + r) * 256 + n] = h;
          Cl[(long)(m + r) * 256 + n] = f2bf_rn(v - bf2f(h));
        }
      } else {  // EPI == 2
        float vb = bias[n];
        int spk = n >> 8, c = n & 255;
        int b = m >> 11, l = m & 2047;
        float4v v;
#pragma unroll
        for (int r = 0; r < 4; ++r) {
          float t = acc[i][j][r] + vb;
          v[r] = t > 0.f ? t : 0.f;
        }
        *(float4v*)&C[(((long)(spk * BATCH + b)) * CIN + c) * L_SEQ + l] = v;
      }
    }
  }
}

// ------ depthwise causal conv(4) + bias + SiLU -> xc hi/lo planes (2 elems/thread) ------
__global__ __launch_bounds__(256) void conv_silu(const float* __restrict__ xr,
                                                 const float* __restrict__ cw,
                                                 const float* __restrict__ cb,
                                                 u16* __restrict__ xch, u16* __restrict__ xcl) {
  int idx = blockIdx.x * 256 + threadIdx.x;  // over M_ROWS*256 pairs
  int d = (idx & 255) * 2;
  int ml = idx >> 8;
  int l = ml & 2047;
  float a0 = cb[d], a1 = cb[d + 1];
  const float* w = cw + d * 4;
#pragma unroll
  for (int k = 0; k < 4; ++k) {
    int ll = l + k - 3;
    if (ll >= 0) {
      float2v xv = *(const float2v*)&xr[(long)(ml + k - 3) * 512 + d];
      a0 += w[k] * xv[0];
      a1 += w[4 + k] * xv[1];
    }
  }
  float v0 = a0 / (1.f + __expf(-a0));
  float v1 = a1 / (1.f + __expf(-a1));
  u16 h0 = f2bf_rn(v0), h1 = f2bf_rn(v1);
  *(ushort2v*)&xch[(long)ml * 512 + d] = (ushort2v){h0, h1};
  *(ushort2v*)&xcl[(long)ml * 512 + d] =
      (ushort2v){f2bf_rn(v0 - bf2f(h0)), f2bf_rn(v1 - bf2f(h1))};
}

// ---------------- chunked selective scan: thread per (b,d), 16 states in registers ------------
__global__ __launch_bounds__(256) void scan_pass1(const float* __restrict__ delta,
                                                  const u16* __restrict__ xch,
                                                  const u16* __restrict__ xcl,
                                                  const float* __restrict__ bc,
                                                  const float* __restrict__ A_log,
                                                  float* __restrict__ P,
                                                  float* __restrict__ Hl) {
  int b = blockIdx.z, c = blockIdx.y;
  int tid = threadIdx.x;
  int d = blockIdx.x * 256 + tid;
  __shared__ float sBC[LC][32];
  const long base = (long)b * L_SEQ + (long)c * LC;
  ((float4v*)sBC)[tid] = ((const float4v*)&bc[base * 32])[tid];
  float Aval[16];
  {
    float4v a[4];
#pragma unroll
    for (int g = 0; g < 4; ++g) a[g] = *(const float4v*)&A_log[d * 16 + g * 4];
#pragma unroll
    for (int s = 0; s < 16; ++s) Aval[s] = -__expf(a[s >> 2][s & 3]);
  }
  __syncthreads();
  float h[16];
#pragma unroll
  for (int s = 0; s < 16; ++s) h[s] = 0.f;
  float sd = 0.f;
#pragma unroll 4
  for (int t = 0; t < LC; ++t) {
    long off = (base + t) * 512 + d;
    float dlv = delta[off];
    float xv = bf2f(xch[off]) + bf2f(xcl[off]);
    float w = dlv * xv;
    sd += dlv;
    float4v Bv[4];
#pragma unroll
    for (int g = 0; g < 4; ++g) Bv[g] = *(const float4v*)&sBC[t][g * 4];
#pragma unroll
    for (int s = 0; s < 16; ++s) {
      float dA = __expf(dlv * Aval[s]);
      h[s] = dA * h[s] + w * Bv[s >> 2][s & 3];
    }
  }
  long idx = (((long)b * NC + c) * 512 + d) * 16;
#pragma unroll
  for (int g = 0; g < 4; ++g) {
    float4v pv, hv;
#pragma unroll
    for (int e = 0; e < 4; ++e) {
      pv[e] = __expf(Aval[g * 4 + e] * sd);
      hv[e] = h[g * 4 + e];
    }
    *(float4v*)&P[idx + g * 4] = pv;
    *(float4v*)&Hl[idx + g * 4] = hv;
  }
}

__global__ __launch_bounds__(256) void scan_combine(const float* __restrict__ P,
                                                    const float* __restrict__ Hl,
                                                    float* __restrict__ H0) {
  int idx = blockIdx.x * 256 + threadIdx.x;  // over B*512*16 = 65536
  int b = idx >> 13;
  int ds = idx & 8191;
  float h = 0.f;
#pragma unroll 8
  for (int c = 0; c < NC; ++c) {
    long off = (((long)b * NC + c) << 13) + ds;
    H0[off] = h;
    h = P[off] * h + Hl[off];
  }
}

__global__ __launch_bounds__(256) void scan_pass2(const float* __restrict__ delta,
                                                  u16* __restrict__ yh, u16* __restrict__ yl,
                                                  const u16* __restrict__ xch,
                                                  const u16* __restrict__ xcl,
                                                  const float* __restrict__ bc,
                                                  const float* __restrict__ z,
                                                  const float* __restrict__ A_log,
                                                  const float* __restrict__ Dp,
                                                  const float* __restrict__ H0) {
  int b = blockIdx.z, c = blockIdx.y;
  int tid = threadIdx.x;
  int d = blockIdx.x * 256 + tid;
  __shared__ float sBC[LC][32];
  const long base = (long)b * L_SEQ + (long)c * LC;
  ((float4v*)sBC)[tid] = ((const float4v*)&bc[base * 32])[tid];
  float Aval[16];
  {
    float4v a[4];
#pragma unroll
    for (int g = 0; g < 4; ++g) a[g] = *(const float4v*)&A_log[d * 16 + g * 4];
#pragma unroll
    for (int s = 0; s < 16; ++s) Aval[s] = -__expf(a[s >> 2][s & 3]);
  }
  float Dval = Dp[d];
  float h[16];
  {
    long hidx = (((long)b * NC + c) * 512 + d) * 16;
#pragma unroll
    for (int g = 0; g < 4; ++g) {
      float4v hv = *(const float4v*)&H0[hidx + g * 4];
#pragma unroll
      for (int e = 0; e < 4; ++e) h[g * 4 + e] = hv[e];
    }
  }
  __syncthreads();
#pragma unroll 4
  for (int t = 0; t < LC; ++t) {
    long off = (base + t) * 512 + d;
    float dlv = delta[off];
    float xv = bf2f(xch[off]) + bf2f(xcl[off]);
    float zv = z[off];
    float w = dlv * xv;
    float4v Bv[4], Cv[4];
#pragma unroll
    for (int g = 0; g < 4; ++g) {
      Bv[g] = *(const float4v*)&sBC[t][g * 4];
      Cv[g] = *(const float4v*)&sBC[t][16 + g * 4];
    }
    float ya = 0.f, yb = 0.f, yc2 = 0.f, yd = 0.f;
#pragma unroll
    for (int s = 0; s < 4; ++s) {
      float dA = __expf(dlv * Aval[s]);
      h[s] = dA * h[s] + w * Bv[0][s];
      ya += h[s] * Cv[0][s];
    }
#pragma unroll
    for (int s = 4; s < 8; ++s) {
      float dA = __expf(dlv * Aval[s]);
      h[s] = dA * h[s] + w * Bv[1][s - 4];
      yb += h[s] * Cv[1][s - 4];
    }
#pragma unroll
    for (int s = 8; s < 12; ++s) {
      float dA = __expf(dlv * Aval[s]);
      h[s] = dA * h[s] + w * Bv[2][s - 8];
      yc2 += h[s] * Cv[2][s - 8];
    }
#pragma unroll
    for (int s = 12; s < 16; ++s) {
      float dA = __expf(dlv * Aval[s]);
      h[s] = dA * h[s] + w * Bv[3][s - 12];
      yd += h[s] * Cv[3][s - 12];
    }
    float yv = (ya + yb) + (yc2 + yd);
    float yf = (yv + xv * Dval) * (zv / (1.f + __expf(-zv)));
    u16 hh = f2bf_rn(yf);
    yh[off] = hh;
    yl[off] = f2bf_rn(yf - bf2f(hh));
  }
}

extern "C" void kernel_launch(void* const* d_in, const int* in_sizes, int n_in, void* d_out,
                              int out_size, void* d_ws, size_t ws_size, hipStream_t stream) {
  const float* input = (const float*)d_in[0];
  const float* in_proj_w = (const float*)d_in[1];
  const float* conv_w = (const float*)d_in[2];
  const float* conv_b = (const float*)d_in[3];
  const float* x_proj_w = (const float*)d_in[4];
  const float* dt_proj_w = (const float*)d_in[5];
  const float* dt_proj_b = (const float*)d_in[6];
  const float* A_log = (const float*)d_in[7];
  const float* Dp = (const float*)d_in[8];
  const float* out_proj_w = (const float*)d_in[9];
  const float* out_lin_w = (const float*)d_in[10];
  const float* out_lin_b = (const float*)d_in[11];

  char* ws = (char*)d_ws;
  u16* buf_xh = (u16*)(ws);                  // 8.39 MB
  u16* buf_xl = (u16*)(ws + 8388608);        // 8.39 MB (region hosts H0 during scan)
  float* buf_xr = (float*)(ws + 16777216);   // 32 MB fp32 (P alias; then yh/yl)
  float* buf_z = (float*)(ws + 50331648);    // 32 MB fp32
  u16* buf_xch = (u16*)(ws + 83886080);      // 16 MB
  u16* buf_xcl = (u16*)(ws + 100663296);     // 16 MB
  float* buf_bc = (float*)(ws + 117440512);  // 2 MB (M_ROWS x 32)
  u16* buf_wch = (u16*)(ws + 119537664);     // 0.5 MB
  u16* buf_wcl = (u16*)(ws + 120061952);     // 0.5 MB
  float* buf_dy = (float*)(ws + 120586240);  // 32 MB fp32 delta
  u16* buf_wd0h = (u16*)(ws + 154140672);    // 640x512 planes
  u16* buf_wd0l = (u16*)(ws + 154796032);
  u16* buf_wd1h = (u16*)(ws + 155451392);
  u16* buf_wd1l = (u16*)(ws + 156106752);
  u16* buf_wth = (u16*)(ws + 156762112);     // 0.5 MB reusable weight scratch
  u16* buf_wtl = (u16*)(ws + 157286400);
  float* buf_P = buf_xr;                     // 16 MB
  float* buf_Hl = (float*)(ws + 33554432);   // 16 MB
  float* buf_H0 = (float*)ws;                // 16.78 MB (x planes dead during scan)
  u16* buf_yh = (u16*)buf_xr;                // 16 MB (P dead after combine)
  u16* buf_yl = (u16*)(ws + 33554432);       // 16 MB (Hl dead after combine)

  build_wd<<<dim3(2, 640), 256, 0, stream>>>(x_proj_w, dt_proj_w, buf_wd0h, buf_wd0l);
  build_wd<<<dim3(2, 640), 256, 0, stream>>>(x_proj_w + 48 * 512, dt_proj_w + 512 * 16, buf_wd1h,
                                             buf_wd1l);
  build_wcomb<<<dim3(2, 512), 256, 0, stream>>>(out_lin_w, out_proj_w + (long)256 * 512, buf_wch,
                                                buf_wcl);
  transpose_in<<<dim3(64, 8, 8), dim3(32, 8), 0, stream>>>(input, buf_xh, buf_xl);

  for (int i = 0; i < 2; ++i) {
    split_pack<<<1024, 256, 0, stream>>>(in_proj_w + (long)i * 1024 * 256, buf_wth, buf_wtl,
                                         1024 * 256);
    gemm_mfma<3><<<dim3(8, 128), 256, 0, stream>>>(buf_xh, buf_xl, 256, buf_wth, buf_wtl, 256,
                                                   buf_xr, buf_z, nullptr, nullptr, nullptr);
    conv_silu<<<16384, 256, 0, stream>>>(buf_xr, conv_w + i * 512 * 4, conv_b + i * 512, buf_xch,
                                         buf_xcl);
    gemm_mfma<4><<<dim3(5, 128), 256, 0, stream>>>(
        buf_xch, buf_xcl, 512, (i == 0) ? buf_wd0h : buf_wd1h, (i == 0) ? buf_wd0l : buf_wd1l,
        512, buf_dy, buf_bc, nullptr, nullptr, dt_proj_b + i * 512);
    scan_pass1<<<dim3(2, NC, 8), 256, 0, stream>>>(buf_dy, buf_xch, buf_xcl, buf_bc,
                                                   A_log + (long)i * 512 * 16, buf_P, buf_Hl);
    scan_combine<<<256, 256, 0, stream>>>(buf_P, buf_Hl, buf_H0);
    scan_pass2<<<dim3(2, NC, 8), 256, 0, stream>>>(buf_dy, buf_yh, buf_yl, buf_xch, buf_xcl,
                                                   buf_bc, buf_z, A_log + (long)i * 512 * 16,
                                                   Dp + i * 512, buf_H0);
    if (i == 0) {
      split_pack<<<512, 256, 0, stream>>>(out_proj_w, buf_wth, buf_wtl, 256 * 512);
      gemm_mfma<5><<<dim3(2, 128), 256, 0, stream>>>(buf_yh, buf_yl, 512, buf_wth, buf_wtl, 512,
                                                     nullptr, nullptr, buf_xh, buf_xl, nullptr);
    } else {
      gemm_mfma<2><<<dim3(4, 128), 256, 0, stream>>>(buf_yh, buf_yl, 512, buf_wch, buf_wcl, 512,
                                                     (float*)d_out, nullptr, nullptr, nullptr,
                                                     out_lin_b);
    }
  }
}

// Round 9
// 568.144 us; speedup vs baseline: 1.2175x; 1.2175x over previous
//
#include <hip/hip_runtime.h>
#include <cmath>

#define L_SEQ 2048
#define BATCH 8
#define CIN 256
#define DIN 512
#define M_ROWS (BATCH * L_SEQ)  // 16384
#define NC 64                   // scan chunks
#define LC 32                   // chunk length

typedef __attribute__((ext_vector_type(8))) short short8;
typedef __attribute__((ext_vector_type(2))) unsigned short ushort2v;
typedef __attribute__((ext_vector_type(4))) unsigned short ushort4v;
typedef __attribute__((ext_vector_type(4))) float float4v;
typedef unsigned short u16;

__device__ inline u16 f2bf_rn(float x) {
  union { float f; unsigned u; } v;
  v.f = x;
  unsigned r = v.u + 0x7FFF + ((v.u >> 16) & 1);
  return (u16)(r >> 16);
}
__device__ inline float bf2f(u16 h) {
  union { unsigned u; float f; } v;
  v.u = ((unsigned)h) << 16;
  return v.f;
}

// async 16B global->LDS (gfx950). LDS dest = wave-uniform base + lane*16.
__device__ inline void gl_lds16(const u16* g, u16* l) {
  __builtin_amdgcn_global_load_lds(
      (const __attribute__((address_space(1))) unsigned int*)(const void*)g,
      (__attribute__((address_space(3))) unsigned int*)(void*)l, 16, 0, 0);
}

// ---------------- transpose (B,C,L) -> (B,L,C), hi/lo bf16 planes ----------------
__global__ __launch_bounds__(256) void transpose_in(const float* __restrict__ in,
                                                    u16* __restrict__ xh, u16* __restrict__ xl) {
  __shared__ float tile[32][33];
  int b = blockIdx.z;
  int l0 = blockIdx.x * 32, c0 = blockIdx.y * 32;
  int tx = threadIdx.x, ty = threadIdx.y;  // 32 x 8
#pragma unroll
  for (int k = 0; k < 4; ++k)
    tile[ty + k * 8][tx] = in[(long)(b * CIN + c0 + ty + k * 8) * L_SEQ + l0 + tx];
  __syncthreads();
#pragma unroll
  for (int k = 0; k < 4; ++k) {
    float v = tile[tx][ty + k * 8];
    long o = (long)(b * L_SEQ + l0 + ty + k * 8) * CIN + c0 + tx;
    u16 h = f2bf_rn(v);
    xh[o] = h;
    xl[o] = f2bf_rn(v - bf2f(h));
  }
}

// ---------------- weight packing to planes ----------------
__global__ __launch_bounds__(256) void split_pack(const float* __restrict__ in,
                                                  u16* __restrict__ oh, u16* __restrict__ ol,
                                                  int n) {
  int i = blockIdx.x * 256 + threadIdx.x;
  if (i < n) {
    float v = in[i];
    u16 h = f2bf_rn(v);
    oh[i] = h;
    ol[i] = f2bf_rn(v - bf2f(h));
  }
}

// Wd (640 x 512): rows 0..511 = dt_proj_w @ x_proj_w[0:16]; 512..543 = B,C rows; rest 0
__global__ __launch_bounds__(256) void build_wd(const float* __restrict__ xpw,
                                                const float* __restrict__ dtw,
                                                u16* __restrict__ Wh, u16* __restrict__ Wl) {
  int k = blockIdx.x * 256 + threadIdx.x;  // 0..511
  int n = blockIdx.y;                      // 0..639
  float v;
  if (n < 512) {
    v = 0.f;
#pragma unroll
    for (int r = 0; r < 16; ++r) v += dtw[n * 16 + r] * xpw[r * 512 + k];
  } else if (n < 544) {
    v = xpw[(16 + n - 512) * 512 + k];
  } else {
    v = 0.f;
  }
  u16 h = f2bf_rn(v);
  Wh[(long)n * 512 + k] = h;
  Wl[(long)n * 512 + k] = f2bf_rn(v - bf2f(h));
}

// W_comb (512 x 512): out_lin_w (512x256) @ out_proj_w[layer1] (256x512)
__global__ __launch_bounds__(256) void build_wcomb(const float* __restrict__ olw,
                                                   const float* __restrict__ opw,
                                                   u16* __restrict__ Wh, u16* __restrict__ Wl) {
  int d = blockIdx.x * 256 + threadIdx.x;  // 0..511
  int o = blockIdx.y;                      // 0..511
  float v = 0.f;
#pragma unroll 4
  for (int c = 0; c < 256; ++c) v += olw[o * 256 + c] * opw[(long)c * 512 + d];
  u16 h = f2bf_rn(v);
  Wh[(long)o * 512 + d] = h;
  Wl[(long)o * 512 + d] = f2bf_rn(v - bf2f(h));
}

// ---------------- bf16x3 MFMA GEMM, async staging + XCD-aware swizzle ----------------
// Linear grid of 128*NBN blocks. xcd = g&7 gets m-tiles [xcd*16, xcd*16+16) x all NBN n-tiles,
// so the NBN blocks sharing an A-tile run concurrently on ONE XCD's L2 (A fetched once/XCD).
// EPI 2: relu(v+bias[n]) scatter to (spk,b,c,l) fp32 (final).
// EPI 3: split fp32 store: n<512 -> C (xr, stride 512); else C2 (z, stride 512).
// EPI 4: n<512: softplus(v+bias[n]) -> C (delta, 512); 512<=n<544 -> C2 (bc, 32); else skip.
// EPI 5: hi/lo plane store -> Ch/Cl (stride 256).
template <int EPI, int NBN>
__global__ __launch_bounds__(256) void gemm_mfma(const u16* __restrict__ Ahp,
                                                 const u16* __restrict__ Alp, int lda,
                                                 const u16* __restrict__ Whp,
                                                 const u16* __restrict__ Wlp, int K,
                                                 float* __restrict__ C, float* __restrict__ C2,
                                                 u16* __restrict__ Ch, u16* __restrict__ Cl,
                                                 const float* __restrict__ bias) {
  __shared__ u16 Ah[128 * 32], Al[128 * 32];
  __shared__ u16 Wh[128 * 32], Wl[128 * 32];
  int g = blockIdx.x;
  int bm = (g & 7) * 16 + (g >> 3) / NBN;
  int bn = (g >> 3) % NBN;
  long m0 = (long)bm * 128, n0 = (long)bn * 128;
  int tid = threadIdx.x;
  int w = tid >> 6, L = tid & 63;
  int q = L >> 4, r16 = L & 15;
  int wm = (w >> 1) * 64, wn = (w & 1) * 64;
  float4v acc[4][4];
#pragma unroll
  for (int i = 0; i < 4; ++i)
#pragma unroll
    for (int j = 0; j < 4; ++j) acc[i][j] = (float4v){0.f, 0.f, 0.f, 0.f};

  int lrow = L >> 2;       // row within 16-row chunk
  int lcol = (L & 3) * 8;  // half-offset within 64 B row

  for (int k0 = 0; k0 < K; k0 += 32) {
    // 8 chunks of 1024 B per array; wave w stages chunks {w, w+4} of each array
#pragma unroll
    for (int is = 0; is < 2; ++is) {
      int chunk = w + is * 4;
      int row = chunk * 16 + lrow;
      long ga = (m0 + row) * (long)lda + k0 + lcol;
      long gw = (n0 + row) * (long)K + k0 + lcol;
      gl_lds16(&Ahp[ga], &Ah[chunk * 512]);
      gl_lds16(&Alp[ga], &Al[chunk * 512]);
      gl_lds16(&Whp[gw], &Wh[chunk * 512]);
      gl_lds16(&Wlp[gw], &Wl[chunk * 512]);
    }
    __syncthreads();
    short8 ah[4], al[4], bh[4], bl[4];
#pragma unroll
    for (int i = 0; i < 4; ++i) {
      int mr = wm + i * 16 + r16;
      ah[i] = *(const short8*)&Ah[mr * 32 + q * 8];
      al[i] = *(const short8*)&Al[mr * 32 + q * 8];
    }
#pragma unroll
    for (int j = 0; j < 4; ++j) {
      int nr = wn + j * 16 + r16;
      bh[j] = *(const short8*)&Wh[nr * 32 + q * 8];
      bl[j] = *(const short8*)&Wl[nr * 32 + q * 8];
    }
#pragma unroll
    for (int i = 0; i < 4; ++i)
#pragma unroll
      for (int j = 0; j < 4; ++j) {
        acc[i][j] = __builtin_amdgcn_mfma_f32_16x16x32_bf16(ah[i], bh[j], acc[i][j], 0, 0, 0);
        acc[i][j] = __builtin_amdgcn_mfma_f32_16x16x32_bf16(al[i], bh[j], acc[i][j], 0, 0, 0);
        acc[i][j] = __builtin_amdgcn_mfma_f32_16x16x32_bf16(ah[i], bl[j], acc[i][j], 0, 0, 0);
      }
    __syncthreads();
  }

  // D layout (16x16x32): row = q*4 + r, col = r16
#pragma unroll
  for (int i = 0; i < 4; ++i) {
    int m = (int)m0 + wm + i * 16 + q * 4;
#pragma unroll
    for (int j = 0; j < 4; ++j) {
      int n = (int)n0 + wn + j * 16 + r16;
      if (EPI == 3) {
        float* dst = (n < 512) ? C : C2;
        int nn = n & 511;
#pragma unroll
        for (int r = 0; r < 4; ++r) dst[(long)(m + r) * 512 + nn] = acc[i][j][r];
      } else if (EPI == 4) {
        if (n < 512) {
          float vb = bias[n];
#pragma unroll
          for (int r = 0; r < 4; ++r) {
            float t = acc[i][j][r] + vb;
            t = (t > 20.f) ? t : __logf(1.f + __expf(t));
            C[(long)(m + r) * 512 + n] = t;
          }
        } else if (n < 544) {
#pragma unroll
          for (int r = 0; r < 4; ++r) C2[(long)(m + r) * 32 + (n - 512)] = acc[i][j][r];
        }
      } else if (EPI == 5) {
#pragma unroll
        for (int r = 0; r < 4; ++r) {
          float v = acc[i][j][r];
          u16 h = f2bf_rn(v);
          Ch[(long)(m + r) * 256 + n] = h;
          Cl[(long)(m + r) * 256 + n] = f2bf_rn(v - bf2f(h));
        }
      } else {  // EPI == 2
        float vb = bias[n];
        int spk = n >> 8, c = n & 255;
        int b = m >> 11, l = m & 2047;
        float4v v;
#pragma unroll
        for (int r = 0; r < 4; ++r) {
          float t = acc[i][j][r] + vb;
          v[r] = t > 0.f ? t : 0.f;
        }
        *(float4v*)&C[(((long)(spk * BATCH + b)) * CIN + c) * L_SEQ + l] = v;
      }
    }
  }
}

// ------ depthwise causal conv(4) + bias + SiLU, banded sliding-window ------
// Block = 32-row band x 512 d. Thread: 4 consecutive d, 16 rows, 4-row register window.
// Bands are 32-aligned within a 2048 sequence, so only l0==0 lacks history (zeros).
__global__ __launch_bounds__(256) void conv_silu(const float* __restrict__ xr,
                                                 const float* __restrict__ cw,
                                                 const float* __restrict__ cb,
                                                 u16* __restrict__ xch, u16* __restrict__ xcl) {
  int tid = threadIdx.x;
  int d = (tid & 127) * 4;
  int r0 = blockIdx.x * 32 + (tid >> 7) * 16;  // gridDim.x = M_ROWS/32
  float4v wv[4];
#pragma unroll
  for (int e = 0; e < 4; ++e) wv[e] = *(const float4v*)&cw[(d + e) * 4];
  float4v bias4 = *(const float4v*)&cb[d];
  float4v x0 = {0.f, 0.f, 0.f, 0.f}, x1 = x0, x2 = x0, x3;
  if ((r0 & 2047) != 0) {
    x0 = *(const float4v*)&xr[(long)(r0 - 3) * 512 + d];
    x1 = *(const float4v*)&xr[(long)(r0 - 2) * 512 + d];
    x2 = *(const float4v*)&xr[(long)(r0 - 1) * 512 + d];
  }
#pragma unroll 4
  for (int t = 0; t < 16; ++t) {
    long row = (long)(r0 + t) * 512 + d;
    x3 = *(const float4v*)&xr[row];
    ushort4v oh, ol;
#pragma unroll
    for (int e = 0; e < 4; ++e) {
      float a = bias4[e] + wv[e][0] * x0[e] + wv[e][1] * x1[e] + wv[e][2] * x2[e] +
                wv[e][3] * x3[e];
      float v = a / (1.f + __expf(-a));
      u16 h = f2bf_rn(v);
      oh[e] = h;
      ol[e] = f2bf_rn(v - bf2f(h));
    }
    *(ushort4v*)&xch[row] = oh;
    *(ushort4v*)&xcl[row] = ol;
    x0 = x1;
    x1 = x2;
    x2 = x3;
  }
}

// ---------------- chunked selective scan: thread per (b,d), 16 states in registers ------------
__global__ __launch_bounds__(256) void scan_pass1(const float* __restrict__ delta,
                                                  const u16* __restrict__ xch,
                                                  const u16* __restrict__ xcl,
                                                  const float* __restrict__ bc,
                                                  const float* __restrict__ A_log,
                                                  float* __restrict__ P,
                                                  float* __restrict__ Hl) {
  int b = blockIdx.z, c = blockIdx.y;
  int tid = threadIdx.x;
  int d = blockIdx.x * 256 + tid;
  __shared__ float sBC[LC][32];
  const long base = (long)b * L_SEQ + (long)c * LC;
  ((float4v*)sBC)[tid] = ((const float4v*)&bc[base * 32])[tid];
  float Aval[16];
  {
    float4v a[4];
#pragma unroll
    for (int g = 0; g < 4; ++g) a[g] = *(const float4v*)&A_log[d * 16 + g * 4];
#pragma unroll
    for (int s = 0; s < 16; ++s) Aval[s] = -__expf(a[s >> 2][s & 3]);
  }
  __syncthreads();
  float h[16];
#pragma unroll
  for (int s = 0; s < 16; ++s) h[s] = 0.f;
  float sd = 0.f;
#pragma unroll 4
  for (int t = 0; t < LC; ++t) {
    long off = (base + t) * 512 + d;
    float dlv = delta[off];
    float xv = bf2f(xch[off]) + bf2f(xcl[off]);
    float w = dlv * xv;
    sd += dlv;
    float4v Bv[4];
#pragma unroll
    for (int g = 0; g < 4; ++g) Bv[g] = *(const float4v*)&sBC[t][g * 4];
#pragma unroll
    for (int s = 0; s < 16; ++s) {
      float dA = __expf(dlv * Aval[s]);
      h[s] = dA * h[s] + w * Bv[s >> 2][s & 3];
    }
  }
  long idx = (((long)b * NC + c) * 512 + d) * 16;
#pragma unroll
  for (int g = 0; g < 4; ++g) {
    float4v pv, hv;
#pragma unroll
    for (int e = 0; e < 4; ++e) {
      pv[e] = __expf(Aval[g * 4 + e] * sd);
      hv[e] = h[g * 4 + e];
    }
    *(float4v*)&P[idx + g * 4] = pv;
    *(float4v*)&Hl[idx + g * 4] = hv;
  }
}

__global__ __launch_bounds__(256) void scan_combine(const float* __restrict__ P,
                                                    const float* __restrict__ Hl,
                                                    float* __restrict__ H0) {
  int idx = blockIdx.x * 256 + threadIdx.x;  // over B*512*16 = 65536
  int b = idx >> 13;
  int ds = idx & 8191;
  float h = 0.f;
#pragma unroll 8
  for (int c = 0; c < NC; ++c) {
    long off = (((long)b * NC + c) << 13) + ds;
    H0[off] = h;
    h = P[off] * h + Hl[off];
  }
}

__global__ __launch_bounds__(256) void scan_pass2(const float* __restrict__ delta,
                                                  u16* __restrict__ yh, u16* __restrict__ yl,
                                                  const u16* __restrict__ xch,
                                                  const u16* __restrict__ xcl,
                                                  const float* __restrict__ bc,
                                                  const float* __restrict__ z,
                                                  const float* __restrict__ A_log,
                                                  const float* __restrict__ Dp,
                                                  const float* __restrict__ H0) {
  int b = blockIdx.z, c = blockIdx.y;
  int tid = threadIdx.x;
  int d = blockIdx.x * 256 + tid;
  __shared__ float sBC[LC][32];
  const long base = (long)b * L_SEQ + (long)c * LC;
  ((float4v*)sBC)[tid] = ((const float4v*)&bc[base * 32])[tid];
  float Aval[16];
  {
    float4v a[4];
#pragma unroll
    for (int g = 0; g < 4; ++g) a[g] = *(const float4v*)&A_log[d * 16 + g * 4];
#pragma unroll
    for (int s = 0; s < 16; ++s) Aval[s] = -__expf(a[s >> 2][s & 3]);
  }
  float Dval = Dp[d];
  float h[16];
  {
    long hidx = (((long)b * NC + c) * 512 + d) * 16;
#pragma unroll
    for (int g = 0; g < 4; ++g) {
      float4v hv = *(const float4v*)&H0[hidx + g * 4];
#pragma unroll
      for (int e = 0; e < 4; ++e) h[g * 4 + e] = hv[e];
    }
  }
  __syncthreads();
#pragma unroll 4
  for (int t = 0; t < LC; ++t) {
    long off = (base + t) * 512 + d;
    float dlv = delta[off];
    float xv = bf2f(xch[off]) + bf2f(xcl[off]);
    float zv = z[off];
    float w = dlv * xv;
    float4v Bv[4], Cv[4];
#pragma unroll
    for (int g = 0; g < 4; ++g) {
      Bv[g] = *(const float4v*)&sBC[t][g * 4];
      Cv[g] = *(const float4v*)&sBC[t][16 + g * 4];
    }
    float ya = 0.f, yb = 0.f, yc2 = 0.f, yd = 0.f;
#pragma unroll
    for (int s = 0; s < 4; ++s) {
      float dA = __expf(dlv * Aval[s]);
      h[s] = dA * h[s] + w * Bv[0][s];
      ya += h[s] * Cv[0][s];
    }
#pragma unroll
    for (int s = 4; s < 8; ++s) {
      float dA = __expf(dlv * Aval[s]);
      h[s] = dA * h[s] + w * Bv[1][s - 4];
      yb += h[s] * Cv[1][s - 4];
    }
#pragma unroll
    for (int s = 8; s < 12; ++s) {
      float dA = __expf(dlv * Aval[s]);
      h[s] = dA * h[s] + w * Bv[2][s - 8];
      yc2 += h[s] * Cv[2][s - 8];
    }
#pragma unroll
    for (int s = 12; s < 16; ++s) {
      float dA = __expf(dlv * Aval[s]);
      h[s] = dA * h[s] + w * Bv[3][s - 12];
      yd += h[s] * Cv[3][s - 12];
    }
    float yv = (ya + yb) + (yc2 + yd);
    float yf = (yv + xv * Dval) * (zv / (1.f + __expf(-zv)));
    u16 hh = f2bf_rn(yf);
    yh[off] = hh;
    yl[off] = f2bf_rn(yf - bf2f(hh));
  }
}

extern "C" void kernel_launch(void* const* d_in, const int* in_sizes, int n_in, void* d_out,
                              int out_size, void* d_ws, size_t ws_size, hipStream_t stream) {
  const float* input = (const float*)d_in[0];
  const float* in_proj_w = (const float*)d_in[1];
  const float* conv_w = (const float*)d_in[2];
  const float* conv_b = (const float*)d_in[3];
  const float* x_proj_w = (const float*)d_in[4];
  const float* dt_proj_w = (const float*)d_in[5];
  const float* dt_proj_b = (const float*)d_in[6];
  const float* A_log = (const float*)d_in[7];
  const float* Dp = (const float*)d_in[8];
  const float* out_proj_w = (const float*)d_in[9];
  const float* out_lin_w = (const float*)d_in[10];
  const float* out_lin_b = (const float*)d_in[11];

  char* ws = (char*)d_ws;
  u16* buf_xh = (u16*)(ws);                  // 8.39 MB
  u16* buf_xl = (u16*)(ws + 8388608);        // 8.39 MB (region hosts H0 during scan)
  float* buf_xr = (float*)(ws + 16777216);   // 32 MB fp32 (P alias; then yh/yl)
  float* buf_z = (float*)(ws + 50331648);    // 32 MB fp32
  u16* buf_xch = (u16*)(ws + 83886080);      // 16 MB
  u16* buf_xcl = (u16*)(ws + 100663296);     // 16 MB
  float* buf_bc = (float*)(ws + 117440512);  // 2 MB (M_ROWS x 32)
  u16* buf_wch = (u16*)(ws + 119537664);     // 0.5 MB
  u16* buf_wcl = (u16*)(ws + 120061952);     // 0.5 MB
  float* buf_dy = (float*)(ws + 120586240);  // 32 MB fp32 delta
  u16* buf_wd0h = (u16*)(ws + 154140672);    // 640x512 planes
  u16* buf_wd0l = (u16*)(ws + 154796032);
  u16* buf_wd1h = (u16*)(ws + 155451392);
  u16* buf_wd1l = (u16*)(ws + 156106752);
  u16* buf_wth = (u16*)(ws + 156762112);     // 0.5 MB reusable weight scratch
  u16* buf_wtl = (u16*)(ws + 157286400);
  float* buf_P = buf_xr;                     // 16 MB
  float* buf_Hl = (float*)(ws + 33554432);   // 16 MB
  float* buf_H0 = (float*)ws;                // 16.78 MB (x planes dead during scan)
  u16* buf_yh = (u16*)buf_xr;                // 16 MB (P dead after combine)
  u16* buf_yl = (u16*)(ws + 33554432);       // 16 MB (Hl dead after combine)

  build_wd<<<dim3(2, 640), 256, 0, stream>>>(x_proj_w, dt_proj_w, buf_wd0h, buf_wd0l);
  build_wd<<<dim3(2, 640), 256, 0, stream>>>(x_proj_w + 48 * 512, dt_proj_w + 512 * 16, buf_wd1h,
                                             buf_wd1l);
  build_wcomb<<<dim3(2, 512), 256, 0, stream>>>(out_lin_w, out_proj_w + (long)256 * 512, buf_wch,
                                                buf_wcl);
  transpose_in<<<dim3(64, 8, 8), dim3(32, 8), 0, stream>>>(input, buf_xh, buf_xl);

  for (int i = 0; i < 2; ++i) {
    split_pack<<<1024, 256, 0, stream>>>(in_proj_w + (long)i * 1024 * 256, buf_wth, buf_wtl,
                                         1024 * 256);
    gemm_mfma<3, 8><<<1024, 256, 0, stream>>>(buf_xh, buf_xl, 256, buf_wth, buf_wtl, 256, buf_xr,
                                              buf_z, nullptr, nullptr, nullptr);
    conv_silu<<<512, 256, 0, stream>>>(buf_xr, conv_w + i * 512 * 4, conv_b + i * 512, buf_xch,
                                       buf_xcl);
    gemm_mfma<4, 5><<<640, 256, 0, stream>>>(
        buf_xch, buf_xcl, 512, (i == 0) ? buf_wd0h : buf_wd1h, (i == 0) ? buf_wd0l : buf_wd1l,
        512, buf_dy, buf_bc, nullptr, nullptr, dt_proj_b + i * 512);
    scan_pass1<<<dim3(2, NC, 8), 256, 0, stream>>>(buf_dy, buf_xch, buf_xcl, buf_bc,
                                                   A_log + (long)i * 512 * 16, buf_P, buf_Hl);
    scan_combine<<<256, 256, 0, stream>>>(buf_P, buf_Hl, buf_H0);
    scan_pass2<<<dim3(2, NC, 8), 256, 0, stream>>>(buf_dy, buf_yh, buf_yl, buf_xch, buf_xcl,
                                                   buf_bc, buf_z, A_log + (long)i * 512 * 16,
                                                   Dp + i * 512, buf_H0);
    if (i == 0) {
      split_pack<<<512, 256, 0, stream>>>(out_proj_w, buf_wth, buf_wtl, 256 * 512);
      gemm_mfma<5, 2><<<256, 256, 0, stream>>>(buf_yh, buf_yl, 512, buf_wth, buf_wtl, 512,
                                               nullptr, nullptr, buf_xh, buf_xl, nullptr);
    } else {
      gemm_mfma<2, 4><<<512, 256, 0, stream>>>(buf_yh, buf_yl, 512, buf_wch, buf_wcl, 512,
                                               (float*)d_out, nullptr, nullptr, nullptr,
                                               out_lin_b);
    }
  }
}

// Round 11
// 560.815 us; speedup vs baseline: 1.2334x; 1.0131x over previous
//
#include <hip/hip_runtime.h>
#include <cmath>

#define L_SEQ 2048
#define BATCH 8
#define CIN 256
#define DIN 512
#define M_ROWS (BATCH * L_SEQ)  // 16384
#define NC 64                   // scan chunks
#define LC 32                   // chunk length

typedef __attribute__((ext_vector_type(8))) short short8;
typedef __attribute__((ext_vector_type(4))) unsigned short ushort4v;
typedef __attribute__((ext_vector_type(4))) float float4v;
typedef unsigned short u16;

__device__ inline u16 f2bf_rn(float x) {
  union { float f; unsigned u; } v;
  v.f = x;
  unsigned r = v.u + 0x7FFF + ((v.u >> 16) & 1);
  return (u16)(r >> 16);
}
__device__ inline float bf2f(u16 h) {
  union { unsigned u; float f; } v;
  v.u = ((unsigned)h) << 16;
  return v.f;
}

// async 16B global->LDS (gfx950). LDS dest = wave-uniform base + lane*16.
__device__ inline void gl_lds16(const u16* g, u16* l) {
  __builtin_amdgcn_global_load_lds(
      (const __attribute__((address_space(1))) unsigned int*)(const void*)g,
      (__attribute__((address_space(3))) unsigned int*)(void*)l, 16, 0, 0);
}

// ---------------- transpose (B,C,L) -> (B,L,C), hi/lo bf16 planes ----------------
__global__ __launch_bounds__(256) void transpose_in(const float* __restrict__ in,
                                                    u16* __restrict__ xh, u16* __restrict__ xl) {
  __shared__ float tile[32][33];
  int b = blockIdx.z;
  int l0 = blockIdx.x * 32, c0 = blockIdx.y * 32;
  int tx = threadIdx.x, ty = threadIdx.y;  // 32 x 8
#pragma unroll
  for (int k = 0; k < 4; ++k)
    tile[ty + k * 8][tx] = in[(long)(b * CIN + c0 + ty + k * 8) * L_SEQ + l0 + tx];
  __syncthreads();
#pragma unroll
  for (int k = 0; k < 4; ++k) {
    float v = tile[tx][ty + k * 8];
    long o = (long)(b * L_SEQ + l0 + ty + k * 8) * CIN + c0 + tx;
    u16 h = f2bf_rn(v);
    xh[o] = h;
    xl[o] = f2bf_rn(v - bf2f(h));
  }
}

// ---------------- weight packing to planes ----------------
__global__ __launch_bounds__(256) void split_pack(const float* __restrict__ in,
                                                  u16* __restrict__ oh, u16* __restrict__ ol,
                                                  int n) {
  int i = blockIdx.x * 256 + threadIdx.x;
  if (i < n) {
    float v = in[i];
    u16 h = f2bf_rn(v);
    oh[i] = h;
    ol[i] = f2bf_rn(v - bf2f(h));
  }
}

// Wd (640 x 512): rows 0..511 = dt_proj_w @ x_proj_w[0:16]; 512..543 = B,C rows; rest 0
__global__ __launch_bounds__(256) void build_wd(const float* __restrict__ xpw,
                                                const float* __restrict__ dtw,
                                                u16* __restrict__ Wh, u16* __restrict__ Wl) {
  int k = blockIdx.x * 256 + threadIdx.x;  // 0..511
  int n = blockIdx.y;                      // 0..639
  float v;
  if (n < 512) {
    v = 0.f;
#pragma unroll
    for (int r = 0; r < 16; ++r) v += dtw[n * 16 + r] * xpw[r * 512 + k];
  } else if (n < 544) {
    v = xpw[(16 + n - 512) * 512 + k];
  } else {
    v = 0.f;
  }
  u16 h = f2bf_rn(v);
  Wh[(long)n * 512 + k] = h;
  Wl[(long)n * 512 + k] = f2bf_rn(v - bf2f(h));
}

// W_comb (512 x 512): out_lin_w (512x256) @ out_proj_w[layer1] (256x512)
__global__ __launch_bounds__(256) void build_wcomb(const float* __restrict__ olw,
                                                   const float* __restrict__ opw,
                                                   u16* __restrict__ Wh, u16* __restrict__ Wl) {
  int d = blockIdx.x * 256 + threadIdx.x;  // 0..511
  int o = blockIdx.y;                      // 0..511
  float v = 0.f;
#pragma unroll 4
  for (int c = 0; c < 256; ++c) v += olw[o * 256 + c] * opw[(long)c * 512 + d];
  u16 h = f2bf_rn(v);
  Wh[(long)o * 512 + d] = h;
  Wl[(long)o * 512 + d] = f2bf_rn(v - bf2f(h));
}

// ---------------- bf16x3 MFMA GEMM, 128x64 tiles, async staging + XCD swizzle ----------------
// Tile 128m x 64n. NBN = n-tiles of 64 (MUST equal N/64 of the weight). Linear grid 128*NBN;
// xcd g&7 owns m-tiles [xcd*16,xcd*16+16) x all n-tiles -> A served from one XCD's L2.
// 4 waves: wave w -> m half (w>>1)*64, n half (w&1)*32; acc 4x2 of 16x16.
// EPI 2: relu(v+bias[n]) scatter to (spk,b,c,l) fp32 (final).
// EPI 3: split fp32 store: n<512 -> C (xr, stride 512); else C2 (z, stride 512).
// EPI 4: n<512: softplus(v+bias[n]) -> C (delta, 512); 512<=n<544 -> C2 (bc, 32); else skip.
// EPI 5: hi/lo plane store -> Ch/Cl (stride 256).
template <int EPI, int NBN>
__global__ __launch_bounds__(256) void gemm_mfma(const u16* __restrict__ Ahp,
                                                 const u16* __restrict__ Alp, int lda,
                                                 const u16* __restrict__ Whp,
                                                 const u16* __restrict__ Wlp, int K,
                                                 float* __restrict__ C, float* __restrict__ C2,
                                                 u16* __restrict__ Ch, u16* __restrict__ Cl,
                                                 const float* __restrict__ bias) {
  __shared__ u16 Ah[128 * 32], Al[128 * 32];
  __shared__ u16 Wh[64 * 32], Wl[64 * 32];
  int g = blockIdx.x;
  int bm = (g & 7) * 16 + (g >> 3) / NBN;
  int bn = (g >> 3) % NBN;
  long m0 = (long)bm * 128, n0 = (long)bn * 64;
  int tid = threadIdx.x;
  int w = tid >> 6, L = tid & 63;
  int q = L >> 4, r16 = L & 15;
  int wm = (w >> 1) * 64, wn = (w & 1) * 32;
  float4v acc[4][2];
#pragma unroll
  for (int i = 0; i < 4; ++i)
#pragma unroll
    for (int j = 0; j < 2; ++j) acc[i][j] = (float4v){0.f, 0.f, 0.f, 0.f};

  int lrow = L >> 2;       // row within 16-row chunk
  int lcol = (L & 3) * 8;  // half-offset within 64 B row

  for (int k0 = 0; k0 < K; k0 += 32) {
    // A: 8 chunks/plane (wave w -> {w, w+4}); W: 4 chunks/plane (wave w -> {w})
#pragma unroll
    for (int is = 0; is < 2; ++is) {
      int chunk = w + is * 4;
      int row = chunk * 16 + lrow;
      long ga = (m0 + row) * (long)lda + k0 + lcol;
      gl_lds16(&Ahp[ga], &Ah[chunk * 512]);
      gl_lds16(&Alp[ga], &Al[chunk * 512]);
    }
    {
      int row = w * 16 + lrow;
      long gw = (n0 + row) * (long)K + k0 + lcol;
      gl_lds16(&Whp[gw], &Wh[w * 512]);
      gl_lds16(&Wlp[gw], &Wl[w * 512]);
    }
    __syncthreads();
    short8 ah[4], al[4], bh[2], bl[2];
#pragma unroll
    for (int i = 0; i < 4; ++i) {
      int mr = wm + i * 16 + r16;
      ah[i] = *(const short8*)&Ah[mr * 32 + q * 8];
      al[i] = *(const short8*)&Al[mr * 32 + q * 8];
    }
#pragma unroll
    for (int j = 0; j < 2; ++j) {
      int nr = wn + j * 16 + r16;
      bh[j] = *(const short8*)&Wh[nr * 32 + q * 8];
      bl[j] = *(const short8*)&Wl[nr * 32 + q * 8];
    }
#pragma unroll
    for (int i = 0; i < 4; ++i)
#pragma unroll
      for (int j = 0; j < 2; ++j) {
        acc[i][j] = __builtin_amdgcn_mfma_f32_16x16x32_bf16(ah[i], bh[j], acc[i][j], 0, 0, 0);
        acc[i][j] = __builtin_amdgcn_mfma_f32_16x16x32_bf16(al[i], bh[j], acc[i][j], 0, 0, 0);
        acc[i][j] = __builtin_amdgcn_mfma_f32_16x16x32_bf16(ah[i], bl[j], acc[i][j], 0, 0, 0);
      }
    __syncthreads();
  }

  // D layout (16x16x32): row = q*4 + r, col = r16
#pragma unroll
  for (int i = 0; i < 4; ++i) {
    int m = (int)m0 + wm + i * 16 + q * 4;
#pragma unroll
    for (int j = 0; j < 2; ++j) {
      int n = (int)n0 + wn + j * 16 + r16;
      if (EPI == 3) {
        float* dst = (n < 512) ? C : C2;
        int nn = n & 511;
#pragma unroll
        for (int r = 0; r < 4; ++r) dst[(long)(m + r) * 512 + nn] = acc[i][j][r];
      } else if (EPI == 4) {
        if (n < 512) {
          float vb = bias[n];
#pragma unroll
          for (int r = 0; r < 4; ++r) {
            float t = acc[i][j][r] + vb;
            t = (t > 20.f) ? t : __logf(1.f + __expf(t));
            C[(long)(m + r) * 512 + n] = t;
          }
        } else if (n < 544) {
#pragma unroll
          for (int r = 0; r < 4; ++r) C2[(long)(m + r) * 32 + (n - 512)] = acc[i][j][r];
        }
      } else if (EPI == 5) {
#pragma unroll
        for (int r = 0; r < 4; ++r) {
          float v = acc[i][j][r];
          u16 h = f2bf_rn(v);
          Ch[(long)(m + r) * 256 + n] = h;
          Cl[(long)(m + r) * 256 + n] = f2bf_rn(v - bf2f(h));
        }
      } else {  // EPI == 2
        float vb = bias[n];
        int spk = n >> 8, c = n & 255;
        int b = m >> 11, l = m & 2047;
        float4v v;
#pragma unroll
        for (int r = 0; r < 4; ++r) {
          float t = acc[i][j][r] + vb;
          v[r] = t > 0.f ? t : 0.f;
        }
        *(float4v*)&C[(((long)(spk * BATCH + b)) * CIN + c) * L_SEQ + l] = v;
      }
    }
  }
}

// ------ depthwise causal conv(4) + bias + SiLU, banded sliding-window ------
__global__ __launch_bounds__(256) void conv_silu(const float* __restrict__ xr,
                                                 const float* __restrict__ cw,
                                                 const float* __restrict__ cb,
                                                 u16* __restrict__ xch, u16* __restrict__ xcl) {
  int tid = threadIdx.x;
  int d = (tid & 127) * 4;
  int r0 = blockIdx.x * 32 + (tid >> 7) * 16;  // gridDim.x = M_ROWS/32
  float4v wv[4];
#pragma unroll
  for (int e = 0; e < 4; ++e) wv[e] = *(const float4v*)&cw[(d + e) * 4];
  float4v bias4 = *(const float4v*)&cb[d];
  float4v x0 = {0.f, 0.f, 0.f, 0.f}, x1 = x0, x2 = x0, x3;
  if ((r0 & 2047) != 0) {
    x0 = *(const float4v*)&xr[(long)(r0 - 3) * 512 + d];
    x1 = *(const float4v*)&xr[(long)(r0 - 2) * 512 + d];
    x2 = *(const float4v*)&xr[(long)(r0 - 1) * 512 + d];
  }
#pragma unroll 4
  for (int t = 0; t < 16; ++t) {
    long row = (long)(r0 + t) * 512 + d;
    x3 = *(const float4v*)&xr[row];
    ushort4v oh, ol;
#pragma unroll
    for (int e = 0; e < 4; ++e) {
      float a = bias4[e] + wv[e][0] * x0[e] + wv[e][1] * x1[e] + wv[e][2] * x2[e] +
                wv[e][3] * x3[e];
      float v = a / (1.f + __expf(-a));
      u16 h = f2bf_rn(v);
      oh[e] = h;
      ol[e] = f2bf_rn(v - bf2f(h));
    }
    *(ushort4v*)&xch[row] = oh;
    *(ushort4v*)&xcl[row] = ol;
    x0 = x1;
    x1 = x2;
    x2 = x3;
  }
}

// ---------------- chunked selective scan: thread per (b,d), 16 states in registers ------------
__global__ __launch_bounds__(256) void scan_pass1(const float* __restrict__ delta,
                                                  const u16* __restrict__ xch,
                                                  const u16* __restrict__ xcl,
                                                  const float* __restrict__ bc,
                                                  const float* __restrict__ A_log,
                                                  float* __restrict__ P,
                                                  float* __restrict__ Hl) {
  int b = blockIdx.z, c = blockIdx.y;
  int tid = threadIdx.x;
  int d = blockIdx.x * 256 + tid;
  __shared__ float sBC[LC][32];
  const long base = (long)b * L_SEQ + (long)c * LC;
  ((float4v*)sBC)[tid] = ((const float4v*)&bc[base * 32])[tid];
  float Aval[16];
  {
    float4v a[4];
#pragma unroll
    for (int g = 0; g < 4; ++g) a[g] = *(const float4v*)&A_log[d * 16 + g * 4];
#pragma unroll
    for (int s = 0; s < 16; ++s) Aval[s] = -__expf(a[s >> 2][s & 3]);
  }
  __syncthreads();
  float h[16];
#pragma unroll
  for (int s = 0; s < 16; ++s) h[s] = 0.f;
  float sd = 0.f;
#pragma unroll 4
  for (int t = 0; t < LC; ++t) {
    long off = (base + t) * 512 + d;
    float dlv = delta[off];
    float xv = bf2f(xch[off]) + bf2f(xcl[off]);
    float w = dlv * xv;
    sd += dlv;
    float4v Bv[4];
#pragma unroll
    for (int g = 0; g < 4; ++g) Bv[g] = *(const float4v*)&sBC[t][g * 4];
#pragma unroll
    for (int s = 0; s < 16; ++s) {
      float dA = __expf(dlv * Aval[s]);
      h[s] = dA * h[s] + w * Bv[s >> 2][s & 3];
    }
  }
  long idx = (((long)b * NC + c) * 512 + d) * 16;
#pragma unroll
  for (int g = 0; g < 4; ++g) {
    float4v pv, hv;
#pragma unroll
    for (int e = 0; e < 4; ++e) {
      pv[e] = __expf(Aval[g * 4 + e] * sd);
      hv[e] = h[g * 4 + e];
    }
    *(float4v*)&P[idx + g * 4] = pv;
    *(float4v*)&Hl[idx + g * 4] = hv;
  }
}

__global__ __launch_bounds__(256) void scan_combine(const float* __restrict__ P,
                                                    const float* __restrict__ Hl,
                                                    float* __restrict__ H0) {
  int idx = blockIdx.x * 256 + threadIdx.x;  // over B*512*16 = 65536
  int b = idx >> 13;
  int ds = idx & 8191;
  float h = 0.f;
#pragma unroll 8
  for (int c = 0; c < NC; ++c) {
    long off = (((long)b * NC + c) << 13) + ds;
    H0[off] = h;
    h = P[off] * h + Hl[off];
  }
}

__global__ __launch_bounds__(256) void scan_pass2(const float* __restrict__ delta,
                                                  u16* __restrict__ yh, u16* __restrict__ yl,
                                                  const u16* __restrict__ xch,
                                                  const u16* __restrict__ xcl,
                                                  const float* __restrict__ bc,
                                                  const float* __restrict__ z,
                                                  const float* __restrict__ A_log,
                                                  const float* __restrict__ Dp,
                                                  const float* __restrict__ H0) {
  int b = blockIdx.z, c = blockIdx.y;
  int tid = threadIdx.x;
  int d = blockIdx.x * 256 + tid;
  __shared__ float sBC[LC][32];
  const long base = (long)b * L_SEQ + (long)c * LC;
  ((float4v*)sBC)[tid] = ((const float4v*)&bc[base * 32])[tid];
  float Aval[16];
  {
    float4v a[4];
#pragma unroll
    for (int g = 0; g < 4; ++g) a[g] = *(const float4v*)&A_log[d * 16 + g * 4];
#pragma unroll
    for (int s = 0; s < 16; ++s) Aval[s] = -__expf(a[s >> 2][s & 3]);
  }
  float Dval = Dp[d];
  float h[16];
  {
    long hidx = (((long)b * NC + c) * 512 + d) * 16;
#pragma unroll
    for (int g = 0; g < 4; ++g) {
      float4v hv = *(const float4v*)&H0[hidx + g * 4];
#pragma unroll
      for (int e = 0; e < 4; ++e) h[g * 4 + e] = hv[e];
    }
  }
  __syncthreads();
#pragma unroll 4
  for (int t = 0; t < LC; ++t) {
    long off = (base + t) * 512 + d;
    float dlv = delta[off];
    float xv = bf2f(xch[off]) + bf2f(xcl[off]);
    float zv = z[off];
    float w = dlv * xv;
    float4v Bv[4], Cv[4];
#pragma unroll
    for (int g = 0; g < 4; ++g) {
      Bv[g] = *(const float4v*)&sBC[t][g * 4];
      Cv[g] = *(const float4v*)&sBC[t][16 + g * 4];
    }
    float ya = 0.f, yb = 0.f, yc2 = 0.f, yd = 0.f;
#pragma unroll
    for (int s = 0; s < 4; ++s) {
      float dA = __expf(dlv * Aval[s]);
      h[s] = dA * h[s] + w * Bv[0][s];
      ya += h[s] * Cv[0][s];
    }
#pragma unroll
    for (int s = 4; s < 8; ++s) {
      float dA = __expf(dlv * Aval[s]);
      h[s] = dA * h[s] + w * Bv[1][s - 4];
      yb += h[s] * Cv[1][s - 4];
    }
#pragma unroll
    for (int s = 8; s < 12; ++s) {
      float dA = __expf(dlv * Aval[s]);
      h[s] = dA * h[s] + w * Bv[2][s - 8];
      yc2 += h[s] * Cv[2][s - 8];
    }
#pragma unroll
    for (int s = 12; s < 16; ++s) {
      float dA = __expf(dlv * Aval[s]);
      h[s] = dA * h[s] + w * Bv[3][s - 12];
      yd += h[s] * Cv[3][s - 12];
    }
    float yv = (ya + yb) + (yc2 + yd);
    float yf = (yv + xv * Dval) * (zv / (1.f + __expf(-zv)));
    u16 hh = f2bf_rn(yf);
    yh[off] = hh;
    yl[off] = f2bf_rn(yf - bf2f(hh));
  }
}

extern "C" void kernel_launch(void* const* d_in, const int* in_sizes, int n_in, void* d_out,
                              int out_size, void* d_ws, size_t ws_size, hipStream_t stream) {
  const float* input = (const float*)d_in[0];
  const float* in_proj_w = (const float*)d_in[1];
  const float* conv_w = (const float*)d_in[2];
  const float* conv_b = (const float*)d_in[3];
  const float* x_proj_w = (const float*)d_in[4];
  const float* dt_proj_w = (const float*)d_in[5];
  const float* dt_proj_b = (const float*)d_in[6];
  const float* A_log = (const float*)d_in[7];
  const float* Dp = (const float*)d_in[8];
  const float* out_proj_w = (const float*)d_in[9];
  const float* out_lin_w = (const float*)d_in[10];
  const float* out_lin_b = (const float*)d_in[11];

  char* ws = (char*)d_ws;
  u16* buf_xh = (u16*)(ws);                  // 8.39 MB
  u16* buf_xl = (u16*)(ws + 8388608);        // 8.39 MB (region hosts H0 during scan)
  float* buf_xr = (float*)(ws + 16777216);   // 32 MB fp32 (P alias; then yh/yl)
  float* buf_z = (float*)(ws + 50331648);    // 32 MB fp32
  u16* buf_xch = (u16*)(ws + 83886080);      // 16 MB
  u16* buf_xcl = (u16*)(ws + 100663296);     // 16 MB
  float* buf_bc = (float*)(ws + 117440512);  // 2 MB (M_ROWS x 32)
  u16* buf_wch = (u16*)(ws + 119537664);     // 0.5 MB
  u16* buf_wcl = (u16*)(ws + 120061952);     // 0.5 MB
  float* buf_dy = (float*)(ws + 120586240);  // 32 MB fp32 delta
  u16* buf_wd0h = (u16*)(ws + 154140672);    // 640x512 planes
  u16* buf_wd0l = (u16*)(ws + 154796032);
  u16* buf_wd1h = (u16*)(ws + 155451392);
  u16* buf_wd1l = (u16*)(ws + 156106752);
  u16* buf_wth = (u16*)(ws + 156762112);     // 0.5 MB reusable weight scratch
  u16* buf_wtl = (u16*)(ws + 157286400);
  float* buf_P = buf_xr;                     // 16 MB
  float* buf_Hl = (float*)(ws + 33554432);   // 16 MB
  float* buf_H0 = (float*)ws;                // 16.78 MB (x planes dead during scan)
  u16* buf_yh = (u16*)buf_xr;                // 16 MB (P dead after combine)
  u16* buf_yl = (u16*)(ws + 33554432);       // 16 MB (Hl dead after combine)

  build_wd<<<dim3(2, 640), 256, 0, stream>>>(x_proj_w, dt_proj_w, buf_wd0h, buf_wd0l);
  build_wd<<<dim3(2, 640), 256, 0, stream>>>(x_proj_w + 48 * 512, dt_proj_w + 512 * 16, buf_wd1h,
                                             buf_wd1l);
  build_wcomb<<<dim3(2, 512), 256, 0, stream>>>(out_lin_w, out_proj_w + (long)256 * 512, buf_wch,
                                                buf_wcl);
  transpose_in<<<dim3(64, 8, 8), dim3(32, 8), 0, stream>>>(input, buf_xh, buf_xl);

  for (int i = 0; i < 2; ++i) {
    split_pack<<<1024, 256, 0, stream>>>(in_proj_w + (long)i * 1024 * 256, buf_wth, buf_wtl,
                                         1024 * 256);
    gemm_mfma<3, 16><<<2048, 256, 0, stream>>>(buf_xh, buf_xl, 256, buf_wth, buf_wtl, 256, buf_xr,
                                               buf_z, nullptr, nullptr, nullptr);
    conv_silu<<<512, 256, 0, stream>>>(buf_xr, conv_w + i * 512 * 4, conv_b + i * 512, buf_xch,
                                       buf_xcl);
    gemm_mfma<4, 10><<<1280, 256, 0, stream>>>(
        buf_xch, buf_xcl, 512, (i == 0) ? buf_wd0h : buf_wd1h, (i == 0) ? buf_wd0l : buf_wd1l,
        512, buf_dy, buf_bc, nullptr, nullptr, dt_proj_b + i * 512);
    scan_pass1<<<dim3(2, NC, 8), 256, 0, stream>>>(buf_dy, buf_xch, buf_xcl, buf_bc,
                                                   A_log + (long)i * 512 * 16, buf_P, buf_Hl);
    scan_combine<<<256, 256, 0, stream>>>(buf_P, buf_Hl, buf_H0);
    scan_pass2<<<dim3(2, NC, 8), 256, 0, stream>>>(buf_dy, buf_yh, buf_yl, buf_xch, buf_xcl,
                                                   buf_bc, buf_z, A_log + (long)i * 512 * 16,
                                                   Dp + i * 512, buf_H0);
    if (i == 0) {
      split_pack<<<512, 256, 0, stream>>>(out_proj_w, buf_wth, buf_wtl, 256 * 512);
      gemm_mfma<5, 4><<<512, 256, 0, stream>>>(buf_yh, buf_yl, 512, buf_wth, buf_wtl, 512,
                                               nullptr, nullptr, buf_xh, buf_xl, nullptr);
    } else {
      gemm_mfma<2, 8><<<1024, 256, 0, stream>>>(buf_yh, buf_yl, 512, buf_wch, buf_wcl, 512,
                                                (float*)d_out, nullptr, nullptr, nullptr,
                                                out_lin_b);
    }
  }
}

// Round 12
// 550.949 us; speedup vs baseline: 1.2555x; 1.0179x over previous
//
#include <hip/hip_runtime.h>
#include <cmath>

#define L_SEQ 2048
#define BATCH 8
#define CIN 256
#define DIN 512
#define M_ROWS (BATCH * L_SEQ)  // 16384
#define NC 64                   // scan chunks
#define LC 32                   // chunk length

typedef __attribute__((ext_vector_type(8))) short short8;
typedef __attribute__((ext_vector_type(4))) unsigned short ushort4v;
typedef __attribute__((ext_vector_type(4))) float float4v;
typedef unsigned short u16;

__device__ inline u16 f2bf_rn(float x) {
  union { float f; unsigned u; } v;
  v.f = x;
  unsigned r = v.u + 0x7FFF + ((v.u >> 16) & 1);
  return (u16)(r >> 16);
}
__device__ inline float bf2f(u16 h) {
  union { unsigned u; float f; } v;
  v.u = ((unsigned)h) << 16;
  return v.f;
}

// async 16B global->LDS (gfx950). LDS dest = wave-uniform base + lane*16.
__device__ inline void gl_lds16(const u16* g, u16* l) {
  __builtin_amdgcn_global_load_lds(
      (const __attribute__((address_space(1))) unsigned int*)(const void*)g,
      (__attribute__((address_space(3))) unsigned int*)(void*)l, 16, 0, 0);
}

// ---------------- transpose (B,C,L) -> (B,L,C), hi/lo bf16 planes ----------------
__global__ __launch_bounds__(256) void transpose_in(const float* __restrict__ in,
                                                    u16* __restrict__ xh, u16* __restrict__ xl) {
  __shared__ float tile[32][33];
  int b = blockIdx.z;
  int l0 = blockIdx.x * 32, c0 = blockIdx.y * 32;
  int tx = threadIdx.x, ty = threadIdx.y;  // 32 x 8
#pragma unroll
  for (int k = 0; k < 4; ++k)
    tile[ty + k * 8][tx] = in[(long)(b * CIN + c0 + ty + k * 8) * L_SEQ + l0 + tx];
  __syncthreads();
#pragma unroll
  for (int k = 0; k < 4; ++k) {
    float v = tile[tx][ty + k * 8];
    long o = (long)(b * L_SEQ + l0 + ty + k * 8) * CIN + c0 + tx;
    u16 h = f2bf_rn(v);
    xh[o] = h;
    xl[o] = f2bf_rn(v - bf2f(h));
  }
}

// ---------------- weight packing to planes ----------------
__global__ __launch_bounds__(256) void split_pack(const float* __restrict__ in,
                                                  u16* __restrict__ oh, u16* __restrict__ ol,
                                                  int n) {
  int i = blockIdx.x * 256 + threadIdx.x;
  if (i < n) {
    float v = in[i];
    u16 h = f2bf_rn(v);
    oh[i] = h;
    ol[i] = f2bf_rn(v - bf2f(h));
  }
}

// Wd (640 x 512): rows 0..511 = dt_proj_w @ x_proj_w[0:16]; 512..543 = B,C rows; rest 0
__global__ __launch_bounds__(256) void build_wd(const float* __restrict__ xpw,
                                                const float* __restrict__ dtw,
                                                u16* __restrict__ Wh, u16* __restrict__ Wl) {
  int k = blockIdx.x * 256 + threadIdx.x;  // 0..511
  int n = blockIdx.y;                      // 0..639
  float v;
  if (n < 512) {
    v = 0.f;
#pragma unroll
    for (int r = 0; r < 16; ++r) v += dtw[n * 16 + r] * xpw[r * 512 + k];
  } else if (n < 544) {
    v = xpw[(16 + n - 512) * 512 + k];
  } else {
    v = 0.f;
  }
  u16 h = f2bf_rn(v);
  Wh[(long)n * 512 + k] = h;
  Wl[(long)n * 512 + k] = f2bf_rn(v - bf2f(h));
}

// W_comb (512 x 512): out_lin_w (512x256) @ out_proj_w[layer1] (256x512)
__global__ __launch_bounds__(256) void build_wcomb(const float* __restrict__ olw,
                                                   const float* __restrict__ opw,
                                                   u16* __restrict__ Wh, u16* __restrict__ Wl) {
  int d = blockIdx.x * 256 + threadIdx.x;  // 0..511
  int o = blockIdx.y;                      // 0..511
  float v = 0.f;
#pragma unroll 4
  for (int c = 0; c < 256; ++c) v += olw[o * 256 + c] * opw[(long)c * 512 + d];
  u16 h = f2bf_rn(v);
  Wh[(long)o * 512 + d] = h;
  Wl[(long)o * 512 + d] = f2bf_rn(v - bf2f(h));
}

// ---------------- bf16x3 MFMA GEMM, 128x64 tiles, async staging + XCD swizzle ----------------
// Tile 128m x 64n. NBN = n-tiles of 64 (MUST equal N/64). Linear grid 128*NBN; xcd g&7 owns
// m-tiles [xcd*16,xcd*16+16) x all n-tiles -> A served from one XCD's L2.
// Bank swizzle: within each 16-row LDS chunk, row r stores its 4 k-chunks rotated by (r>>1)&3:
// physical chunk p holds logical q = (p - (r>>1))&3. A 16-lane fragment-read group then covers
// all 32 banks exactly 2x (2-way = free, m136) instead of 8 banks (4-way+).
// EPI 2: relu(v+bias[n]) scatter to (spk,b,c,l) fp32 (final).
// EPI 3: split fp32 store: n<512 -> C (xr, stride 512); else C2 (z, stride 512).
// EPI 4: n<512: softplus(v+bias[n]) -> C (delta, 512); 512<=n<544 -> C2 (bc, 32); else skip.
// EPI 5: hi/lo plane store -> Ch/Cl (stride 256).
template <int EPI, int NBN>
__global__ __launch_bounds__(256) void gemm_mfma(const u16* __restrict__ Ahp,
                                                 const u16* __restrict__ Alp, int lda,
                                                 const u16* __restrict__ Whp,
                                                 const u16* __restrict__ Wlp, int K,
                                                 float* __restrict__ C, float* __restrict__ C2,
                                                 u16* __restrict__ Ch, u16* __restrict__ Cl,
                                                 const float* __restrict__ bias) {
  __shared__ u16 Ah[128 * 32], Al[128 * 32];
  __shared__ u16 Wh[64 * 32], Wl[64 * 32];
  int g = blockIdx.x;
  int bm = (g & 7) * 16 + (g >> 3) / NBN;
  int bn = (g >> 3) % NBN;
  long m0 = (long)bm * 128, n0 = (long)bn * 64;
  int tid = threadIdx.x;
  int w = tid >> 6, L = tid & 63;
  int q = L >> 4, r16 = L & 15;
  int wm = (w >> 1) * 64, wn = (w & 1) * 32;
  float4v acc[4][2];
#pragma unroll
  for (int i = 0; i < 4; ++i)
#pragma unroll
    for (int j = 0; j < 2; ++j) acc[i][j] = (float4v){0.f, 0.f, 0.f, 0.f};

  int lrow = L >> 2;                          // row within 16-row chunk
  int lcol = (((L & 3) - (L >> 3)) & 3) * 8;  // swizzled: fetch logical chunk for phys (L&3)
  int rchunk = (q + (r16 >> 1)) & 3;          // physical chunk holding logical q for row r16

  for (int k0 = 0; k0 < K; k0 += 32) {
    // A: 8 chunks/plane (wave w -> {w, w+4}); W: 4 chunks/plane (wave w -> {w})
#pragma unroll
    for (int is = 0; is < 2; ++is) {
      int chunk = w + is * 4;
      int row = chunk * 16 + lrow;
      long ga = (m0 + row) * (long)lda + k0 + lcol;
      gl_lds16(&Ahp[ga], &Ah[chunk * 512]);
      gl_lds16(&Alp[ga], &Al[chunk * 512]);
    }
    {
      int row = w * 16 + lrow;
      long gw = (n0 + row) * (long)K + k0 + lcol;
      gl_lds16(&Whp[gw], &Wh[w * 512]);
      gl_lds16(&Wlp[gw], &Wl[w * 512]);
    }
    __syncthreads();
    short8 ah[4], al[4], bh[2], bl[2];
#pragma unroll
    for (int i = 0; i < 4; ++i) {
      int mr = wm + i * 16 + r16;
      ah[i] = *(const short8*)&Ah[mr * 32 + rchunk * 8];
      al[i] = *(const short8*)&Al[mr * 32 + rchunk * 8];
    }
#pragma unroll
    for (int j = 0; j < 2; ++j) {
      int nr = wn + j * 16 + r16;
      bh[j] = *(const short8*)&Wh[nr * 32 + rchunk * 8];
      bl[j] = *(const short8*)&Wl[nr * 32 + rchunk * 8];
    }
#pragma unroll
    for (int i = 0; i < 4; ++i)
#pragma unroll
      for (int j = 0; j < 2; ++j) {
        acc[i][j] = __builtin_amdgcn_mfma_f32_16x16x32_bf16(ah[i], bh[j], acc[i][j], 0, 0, 0);
        acc[i][j] = __builtin_amdgcn_mfma_f32_16x16x32_bf16(al[i], bh[j], acc[i][j], 0, 0, 0);
        acc[i][j] = __builtin_amdgcn_mfma_f32_16x16x32_bf16(ah[i], bl[j], acc[i][j], 0, 0, 0);
      }
    __syncthreads();
  }

  // D layout (16x16x32): row = q*4 + r, col = r16
#pragma unroll
  for (int i = 0; i < 4; ++i) {
    int m = (int)m0 + wm + i * 16 + q * 4;
#pragma unroll
    for (int j = 0; j < 2; ++j) {
      int n = (int)n0 + wn + j * 16 + r16;
      if (EPI == 3) {
        float* dst = (n < 512) ? C : C2;
        int nn = n & 511;
#pragma unroll
        for (int r = 0; r < 4; ++r) dst[(long)(m + r) * 512 + nn] = acc[i][j][r];
      } else if (EPI == 4) {
        if (n < 512) {
          float vb = bias[n];
#pragma unroll
          for (int r = 0; r < 4; ++r) {
            float t = acc[i][j][r] + vb;
            t = (t > 20.f) ? t : __logf(1.f + __expf(t));
            C[(long)(m + r) * 512 + n] = t;
          }
        } else if (n < 544) {
#pragma unroll
          for (int r = 0; r < 4; ++r) C2[(long)(m + r) * 32 + (n - 512)] = acc[i][j][r];
        }
      } else if (EPI == 5) {
#pragma unroll
        for (int r = 0; r < 4; ++r) {
          float v = acc[i][j][r];
          u16 h = f2bf_rn(v);
          Ch[(long)(m + r) * 256 + n] = h;
          Cl[(long)(m + r) * 256 + n] = f2bf_rn(v - bf2f(h));
        }
      } else {  // EPI == 2
        float vb = bias[n];
        int spk = n >> 8, c = n & 255;
        int b = m >> 11, l = m & 2047;
        float4v v;
#pragma unroll
        for (int r = 0; r < 4; ++r) {
          float t = acc[i][j][r] + vb;
          v[r] = t > 0.f ? t : 0.f;
        }
        *(float4v*)&C[(((long)(spk * BATCH + b)) * CIN + c) * L_SEQ + l] = v;
      }
    }
  }
}

// ------ depthwise causal conv(4) + bias + SiLU, banded sliding-window ------
__global__ __launch_bounds__(256) void conv_silu(const float* __restrict__ xr,
                                                 const float* __restrict__ cw,
                                                 const float* __restrict__ cb,
                                                 u16* __restrict__ xch, u16* __restrict__ xcl) {
  int tid = threadIdx.x;
  int d = (tid & 127) * 4;
  int r0 = blockIdx.x * 32 + (tid >> 7) * 16;  // gridDim.x = M_ROWS/32
  float4v wv[4];
#pragma unroll
  for (int e = 0; e < 4; ++e) wv[e] = *(const float4v*)&cw[(d + e) * 4];
  float4v bias4 = *(const float4v*)&cb[d];
  float4v x0 = {0.f, 0.f, 0.f, 0.f}, x1 = x0, x2 = x0, x3;
  if ((r0 & 2047) != 0) {
    x0 = *(const float4v*)&xr[(long)(r0 - 3) * 512 + d];
    x1 = *(const float4v*)&xr[(long)(r0 - 2) * 512 + d];
    x2 = *(const float4v*)&xr[(long)(r0 - 1) * 512 + d];
  }
#pragma unroll 4
  for (int t = 0; t < 16; ++t) {
    long row = (long)(r0 + t) * 512 + d;
    x3 = *(const float4v*)&xr[row];
    ushort4v oh, ol;
#pragma unroll
    for (int e = 0; e < 4; ++e) {
      float a = bias4[e] + wv[e][0] * x0[e] + wv[e][1] * x1[e] + wv[e][2] * x2[e] +
                wv[e][3] * x3[e];
      float v = a / (1.f + __expf(-a));
      u16 h = f2bf_rn(v);
      oh[e] = h;
      ol[e] = f2bf_rn(v - bf2f(h));
    }
    *(ushort4v*)&xch[row] = oh;
    *(ushort4v*)&xcl[row] = ol;
    x0 = x1;
    x1 = x2;
    x2 = x3;
  }
}

// ---------------- chunked selective scan: thread per (b,d), 16 states in registers ------------
__global__ __launch_bounds__(256) void scan_pass1(const float* __restrict__ delta,
                                                  const u16* __restrict__ xch,
                                                  const u16* __restrict__ xcl,
                                                  const float* __restrict__ bc,
                                                  const float* __restrict__ A_log,
                                                  float* __restrict__ P,
                                                  float* __restrict__ Hl) {
  int b = blockIdx.z, c = blockIdx.y;
  int tid = threadIdx.x;
  int d = blockIdx.x * 256 + tid;
  __shared__ float sBC[LC][32];
  const long base = (long)b * L_SEQ + (long)c * LC;
  ((float4v*)sBC)[tid] = ((const float4v*)&bc[base * 32])[tid];
  float Aval[16];
  {
    float4v a[4];
#pragma unroll
    for (int g = 0; g < 4; ++g) a[g] = *(const float4v*)&A_log[d * 16 + g * 4];
#pragma unroll
    for (int s = 0; s < 16; ++s) Aval[s] = -__expf(a[s >> 2][s & 3]);
  }
  __syncthreads();
  float h[16];
#pragma unroll
  for (int s = 0; s < 16; ++s) h[s] = 0.f;
  float sd = 0.f;
#pragma unroll 4
  for (int t = 0; t < LC; ++t) {
    long off = (base + t) * 512 + d;
    float dlv = delta[off];
    float xv = bf2f(xch[off]) + bf2f(xcl[off]);
    float w = dlv * xv;
    sd += dlv;
    float4v Bv[4];
#pragma unroll
    for (int g = 0; g < 4; ++g) Bv[g] = *(const float4v*)&sBC[t][g * 4];
#pragma unroll
    for (int s = 0; s < 16; ++s) {
      float dA = __expf(dlv * Aval[s]);
      h[s] = dA * h[s] + w * Bv[s >> 2][s & 3];
    }
  }
  long idx = (((long)b * NC + c) * 512 + d) * 16;
#pragma unroll
  for (int g = 0; g < 4; ++g) {
    float4v pv, hv;
#pragma unroll
    for (int e = 0; e < 4; ++e) {
      pv[e] = __expf(Aval[g * 4 + e] * sd);
      hv[e] = h[g * 4 + e];
    }
    *(float4v*)&P[idx + g * 4] = pv;
    *(float4v*)&Hl[idx + g * 4] = hv;
  }
}

__global__ __launch_bounds__(256) void scan_combine(const float* __restrict__ P,
                                                    const float* __restrict__ Hl,
                                                    float* __restrict__ H0) {
  int idx = blockIdx.x * 256 + threadIdx.x;  // over B*512*16 = 65536
  int b = idx >> 13;
  int ds = idx & 8191;
  float h = 0.f;
#pragma unroll 8
  for (int c = 0; c < NC; ++c) {
    long off = (((long)b * NC + c) << 13) + ds;
    H0[off] = h;
    h = P[off] * h + Hl[off];
  }
}

__global__ __launch_bounds__(256) void scan_pass2(const float* __restrict__ delta,
                                                  u16* __restrict__ yh, u16* __restrict__ yl,
                                                  const u16* __restrict__ xch,
                                                  const u16* __restrict__ xcl,
                                                  const float* __restrict__ bc,
                                                  const float* __restrict__ z,
                                                  const float* __restrict__ A_log,
                                                  const float* __restrict__ Dp,
                                                  const float* __restrict__ H0) {
  int b = blockIdx.z, c = blockIdx.y;
  int tid = threadIdx.x;
  int d = blockIdx.x * 256 + tid;
  __shared__ float sBC[LC][32];
  const long base = (long)b * L_SEQ + (long)c * LC;
  ((float4v*)sBC)[tid] = ((const float4v*)&bc[base * 32])[tid];
  float Aval[16];
  {
    float4v a[4];
#pragma unroll
    for (int g = 0; g < 4; ++g) a[g] = *(const float4v*)&A_log[d * 16 + g * 4];
#pragma unroll
    for (int s = 0; s < 16; ++s) Aval[s] = -__expf(a[s >> 2][s & 3]);
  }
  float Dval = Dp[d];
  float h[16];
  {
    long hidx = (((long)b * NC + c) * 512 + d) * 16;
#pragma unroll
    for (int g = 0; g < 4; ++g) {
      float4v hv = *(const float4v*)&H0[hidx + g * 4];
#pragma unroll
      for (int e = 0; e < 4; ++e) h[g * 4 + e] = hv[e];
    }
  }
  __syncthreads();
#pragma unroll 4
  for (int t = 0; t < LC; ++t) {
    long off = (base + t) * 512 + d;
    float dlv = delta[off];
    float xv = bf2f(xch[off]) + bf2f(xcl[off]);
    float zv = z[off];
    float w = dlv * xv;
    float4v Bv[4], Cv[4];
#pragma unroll
    for (int g = 0; g < 4; ++g) {
      Bv[g] = *(const float4v*)&sBC[t][g * 4];
      Cv[g] = *(const float4v*)&sBC[t][16 + g * 4];
    }
    float ya = 0.f, yb = 0.f, yc2 = 0.f, yd = 0.f;
#pragma unroll
    for (int s = 0; s < 4; ++s) {
      float dA = __expf(dlv * Aval[s]);
      h[s] = dA * h[s] + w * Bv[0][s];
      ya += h[s] * Cv[0][s];
    }
#pragma unroll
    for (int s = 4; s < 8; ++s) {
      float dA = __expf(dlv * Aval[s]);
      h[s] = dA * h[s] + w * Bv[1][s - 4];
      yb += h[s] * Cv[1][s - 4];
    }
#pragma unroll
    for (int s = 8; s < 12; ++s) {
      float dA = __expf(dlv * Aval[s]);
      h[s] = dA * h[s] + w * Bv[2][s - 8];
      yc2 += h[s] * Cv[2][s - 8];
    }
#pragma unroll
    for (int s = 12; s < 16; ++s) {
      float dA = __expf(dlv * Aval[s]);
      h[s] = dA * h[s] + w * Bv[3][s - 12];
      yd += h[s] * Cv[3][s - 12];
    }
    float yv = (ya + yb) + (yc2 + yd);
    float yf = (yv + xv * Dval) * (zv / (1.f + __expf(-zv)));
    u16 hh = f2bf_rn(yf);
    yh[off] = hh;
    yl[off] = f2bf_rn(yf - bf2f(hh));
  }
}

extern "C" void kernel_launch(void* const* d_in, const int* in_sizes, int n_in, void* d_out,
                              int out_size, void* d_ws, size_t ws_size, hipStream_t stream) {
  const float* input = (const float*)d_in[0];
  const float* in_proj_w = (const float*)d_in[1];
  const float* conv_w = (const float*)d_in[2];
  const float* conv_b = (const float*)d_in[3];
  const float* x_proj_w = (const float*)d_in[4];
  const float* dt_proj_w = (const float*)d_in[5];
  const float* dt_proj_b = (const float*)d_in[6];
  const float* A_log = (const float*)d_in[7];
  const float* Dp = (const float*)d_in[8];
  const float* out_proj_w = (const float*)d_in[9];
  const float* out_lin_w = (const float*)d_in[10];
  const float* out_lin_b = (const float*)d_in[11];

  char* ws = (char*)d_ws;
  u16* buf_xh = (u16*)(ws);                  // 8.39 MB
  u16* buf_xl = (u16*)(ws + 8388608);        // 8.39 MB (region hosts H0 during scan)
  float* buf_xr = (float*)(ws + 16777216);   // 32 MB fp32 (P alias; then yh/yl)
  float* buf_z = (float*)(ws + 50331648);    // 32 MB fp32
  u16* buf_xch = (u16*)(ws + 83886080);      // 16 MB
  u16* buf_xcl = (u16*)(ws + 100663296);     // 16 MB
  float* buf_bc = (float*)(ws + 117440512);  // 2 MB (M_ROWS x 32)
  u16* buf_wch = (u16*)(ws + 119537664);     // 0.5 MB
  u16* buf_wcl = (u16*)(ws + 120061952);     // 0.5 MB
  float* buf_dy = (float*)(ws + 120586240);  // 32 MB fp32 delta
  u16* buf_wd0h = (u16*)(ws + 154140672);    // 640x512 planes
  u16* buf_wd0l = (u16*)(ws + 154796032);
  u16* buf_wd1h = (u16*)(ws + 155451392);
  u16* buf_wd1l = (u16*)(ws + 156106752);
  u16* buf_wth = (u16*)(ws + 156762112);     // 0.5 MB reusable weight scratch
  u16* buf_wtl = (u16*)(ws + 157286400);
  float* buf_P = buf_xr;                     // 16 MB
  float* buf_Hl = (float*)(ws + 33554432);   // 16 MB
  float* buf_H0 = (float*)ws;                // 16.78 MB (x planes dead during scan)
  u16* buf_yh = (u16*)buf_xr;                // 16 MB (P dead after combine)
  u16* buf_yl = (u16*)(ws + 33554432);       // 16 MB (Hl dead after combine)

  build_wd<<<dim3(2, 640), 256, 0, stream>>>(x_proj_w, dt_proj_w, buf_wd0h, buf_wd0l);
  build_wd<<<dim3(2, 640), 256, 0, stream>>>(x_proj_w + 48 * 512, dt_proj_w + 512 * 16, buf_wd1h,
                                             buf_wd1l);
  build_wcomb<<<dim3(2, 512), 256, 0, stream>>>(out_lin_w, out_proj_w + (long)256 * 512, buf_wch,
                                                buf_wcl);
  transpose_in<<<dim3(64, 8, 8), dim3(32, 8), 0, stream>>>(input, buf_xh, buf_xl);

  for (int i = 0; i < 2; ++i) {
    split_pack<<<1024, 256, 0, stream>>>(in_proj_w + (long)i * 1024 * 256, buf_wth, buf_wtl,
                                         1024 * 256);
    gemm_mfma<3, 16><<<2048, 256, 0, stream>>>(buf_xh, buf_xl, 256, buf_wth, buf_wtl, 256, buf_xr,
                                               buf_z, nullptr, nullptr, nullptr);
    conv_silu<<<512, 256, 0, stream>>>(buf_xr, conv_w + i * 512 * 4, conv_b + i * 512, buf_xch,
                                       buf_xcl);
    gemm_mfma<4, 10><<<1280, 256, 0, stream>>>(
        buf_xch, buf_xcl, 512, (i == 0) ? buf_wd0h : buf_wd1h, (i == 0) ? buf_wd0l : buf_wd1l,
        512, buf_dy, buf_bc, nullptr, nullptr, dt_proj_b + i * 512);
    scan_pass1<<<dim3(2, NC, 8), 256, 0, stream>>>(buf_dy, buf_xch, buf_xcl, buf_bc,
                                                   A_log + (long)i * 512 * 16, buf_P, buf_Hl);
    scan_combine<<<256, 256, 0, stream>>>(buf_P, buf_Hl, buf_H0);
    scan_pass2<<<dim3(2, NC, 8), 256, 0, stream>>>(buf_dy, buf_yh, buf_yl, buf_xch, buf_xcl,
                                                   buf_bc, buf_z, A_log + (long)i * 512 * 16,
                                                   Dp + i * 512, buf_H0);
    if (i == 0) {
      split_pack<<<512, 256, 0, stream>>>(out_proj_w, buf_wth, buf_wtl, 256 * 512);
      gemm_mfma<5, 4><<<512, 256, 0, stream>>>(buf_yh, buf_yl, 512, buf_wth, buf_wtl, 512,
                                               nullptr, nullptr, buf_xh, buf_xl, nullptr);
    } else {
      gemm_mfma<2, 8><<<1024, 256, 0, stream>>>(buf_yh, buf_yl, 512, buf_wch, buf_wcl, 512,
                                                (float*)d_out, nullptr, nullptr, nullptr,
                                                out_lin_b);
    }
  }
}

// Round 13
// 542.609 us; speedup vs baseline: 1.2748x; 1.0154x over previous
//
#include <hip/hip_runtime.h>
#include <cmath>

#define L_SEQ 2048
#define BATCH 8
#define CIN 256
#define DIN 512
#define M_ROWS (BATCH * L_SEQ)  // 16384
#define NC 64                   // scan chunks
#define LC 32                   // chunk length

typedef __attribute__((ext_vector_type(8))) short short8;
typedef __attribute__((ext_vector_type(4))) unsigned short ushort4v;
typedef __attribute__((ext_vector_type(4))) float float4v;
typedef unsigned short u16;

__device__ inline u16 f2bf_rn(float x) {
  union { float f; unsigned u; } v;
  v.f = x;
  unsigned r = v.u + 0x7FFF + ((v.u >> 16) & 1);
  return (u16)(r >> 16);
}
__device__ inline float bf2f(u16 h) {
  union { unsigned u; float f; } v;
  v.u = ((unsigned)h) << 16;
  return v.f;
}

// async 16B global->LDS (gfx950). LDS dest = wave-uniform base + lane*16.
__device__ inline void gl_lds16(const u16* g, u16* l) {
  __builtin_amdgcn_global_load_lds(
      (const __attribute__((address_space(1))) unsigned int*)(const void*)g,
      (__attribute__((address_space(3))) unsigned int*)(void*)l, 16, 0, 0);
}

// ---------------- transpose (B,C,L) -> (B,L,C), hi/lo bf16 planes ----------------
__global__ __launch_bounds__(256) void transpose_in(const float* __restrict__ in,
                                                    u16* __restrict__ xh, u16* __restrict__ xl) {
  __shared__ float tile[32][33];
  int b = blockIdx.z;
  int l0 = blockIdx.x * 32, c0 = blockIdx.y * 32;
  int tx = threadIdx.x, ty = threadIdx.y;  // 32 x 8
#pragma unroll
  for (int k = 0; k < 4; ++k)
    tile[ty + k * 8][tx] = in[(long)(b * CIN + c0 + ty + k * 8) * L_SEQ + l0 + tx];
  __syncthreads();
#pragma unroll
  for (int k = 0; k < 4; ++k) {
    float v = tile[tx][ty + k * 8];
    long o = (long)(b * L_SEQ + l0 + ty + k * 8) * CIN + c0 + tx;
    u16 h = f2bf_rn(v);
    xh[o] = h;
    xl[o] = f2bf_rn(v - bf2f(h));
  }
}

// ---------------- weight packing to planes ----------------
__global__ __launch_bounds__(256) void split_pack(const float* __restrict__ in,
                                                  u16* __restrict__ oh, u16* __restrict__ ol,
                                                  int n) {
  int i = blockIdx.x * 256 + threadIdx.x;
  if (i < n) {
    float v = in[i];
    u16 h = f2bf_rn(v);
    oh[i] = h;
    ol[i] = f2bf_rn(v - bf2f(h));
  }
}

// Wd (576 x 512): rows 0..511 = dt_proj_w @ x_proj_w[0:16]; 512..543 = B,C rows; 544..575 = 0
__global__ __launch_bounds__(256) void build_wd(const float* __restrict__ xpw,
                                                const float* __restrict__ dtw,
                                                u16* __restrict__ Wh, u16* __restrict__ Wl) {
  int k = blockIdx.x * 256 + threadIdx.x;  // 0..511
  int n = blockIdx.y;                      // 0..575
  float v;
  if (n < 512) {
    v = 0.f;
#pragma unroll
    for (int r = 0; r < 16; ++r) v += dtw[n * 16 + r] * xpw[r * 512 + k];
  } else if (n < 544) {
    v = xpw[(16 + n - 512) * 512 + k];
  } else {
    v = 0.f;
  }
  u16 h = f2bf_rn(v);
  Wh[(long)n * 512 + k] = h;
  Wl[(long)n * 512 + k] = f2bf_rn(v - bf2f(h));
}

// W_comb (512 x 512): out_lin_w (512x256) @ out_proj_w[layer1] (256x512)
__global__ __launch_bounds__(256) void build_wcomb(const float* __restrict__ olw,
                                                   const float* __restrict__ opw,
                                                   u16* __restrict__ Wh, u16* __restrict__ Wl) {
  int d = blockIdx.x * 256 + threadIdx.x;  // 0..511
  int o = blockIdx.y;                      // 0..511
  float v = 0.f;
#pragma unroll 4
  for (int c = 0; c < 256; ++c) v += olw[o * 256 + c] * opw[(long)c * 512 + d];
  u16 h = f2bf_rn(v);
  Wh[(long)o * 512 + d] = h;
  Wl[(long)o * 512 + d] = f2bf_rn(v - bf2f(h));
}

// ---------------- bf16x3 MFMA GEMM, 128x64 tiles, async staging + XCD swizzle ----------------
// Tile 128m x 64n. NBN = N/64. Linear grid 128*NBN; xcd g&7 owns m-tiles [xcd*16,xcd*16+16).
// Bank swizzle: row r stores k-chunks rotated by (r>>1)&3 (all 32 banks 2x — free).
// EPI 2: relu(v+bias[n]) scatter to (spk,b,c,l) fp32 (final) -> C.
// EPI 3: plane split store: n<512 -> Ch/Cl (xr planes, stride 512); else Ch2/Cl2 (z planes).
// EPI 4: n<512: softplus(v+bias[n]) -> Ch/Cl planes (delta, 512); 512<=n<544 -> C2 (bc, 32).
// EPI 5: hi/lo plane store -> Ch/Cl (stride 256).
template <int EPI, int NBN>
__global__ __launch_bounds__(256) void gemm_mfma(const u16* __restrict__ Ahp,
                                                 const u16* __restrict__ Alp, int lda,
                                                 const u16* __restrict__ Whp,
                                                 const u16* __restrict__ Wlp, int K,
                                                 float* __restrict__ C, float* __restrict__ C2,
                                                 u16* __restrict__ Ch, u16* __restrict__ Cl,
                                                 u16* __restrict__ Ch2, u16* __restrict__ Cl2,
                                                 const float* __restrict__ bias) {
  __shared__ u16 Ah[128 * 32], Al[128 * 32];
  __shared__ u16 Wh[64 * 32], Wl[64 * 32];
  int g = blockIdx.x;
  int bm = (g & 7) * 16 + (g >> 3) / NBN;
  int bn = (g >> 3) % NBN;
  long m0 = (long)bm * 128, n0 = (long)bn * 64;
  int tid = threadIdx.x;
  int w = tid >> 6, L = tid & 63;
  int q = L >> 4, r16 = L & 15;
  int wm = (w >> 1) * 64, wn = (w & 1) * 32;
  float4v acc[4][2];
#pragma unroll
  for (int i = 0; i < 4; ++i)
#pragma unroll
    for (int j = 0; j < 2; ++j) acc[i][j] = (float4v){0.f, 0.f, 0.f, 0.f};

  int lrow = L >> 2;                          // row within 16-row chunk
  int lcol = (((L & 3) - (L >> 3)) & 3) * 8;  // swizzled fetch
  int rchunk = (q + (r16 >> 1)) & 3;          // physical chunk for logical q at row r16

  for (int k0 = 0; k0 < K; k0 += 32) {
#pragma unroll
    for (int is = 0; is < 2; ++is) {
      int chunk = w + is * 4;
      int row = chunk * 16 + lrow;
      long ga = (m0 + row) * (long)lda + k0 + lcol;
      gl_lds16(&Ahp[ga], &Ah[chunk * 512]);
      gl_lds16(&Alp[ga], &Al[chunk * 512]);
    }
    {
      int row = w * 16 + lrow;
      long gw = (n0 + row) * (long)K + k0 + lcol;
      gl_lds16(&Whp[gw], &Wh[w * 512]);
      gl_lds16(&Wlp[gw], &Wl[w * 512]);
    }
    __syncthreads();
    short8 ah[4], al[4], bh[2], bl[2];
#pragma unroll
    for (int i = 0; i < 4; ++i) {
      int mr = wm + i * 16 + r16;
      ah[i] = *(const short8*)&Ah[mr * 32 + rchunk * 8];
      al[i] = *(const short8*)&Al[mr * 32 + rchunk * 8];
    }
#pragma unroll
    for (int j = 0; j < 2; ++j) {
      int nr = wn + j * 16 + r16;
      bh[j] = *(const short8*)&Wh[nr * 32 + rchunk * 8];
      bl[j] = *(const short8*)&Wl[nr * 32 + rchunk * 8];
    }
#pragma unroll
    for (int i = 0; i < 4; ++i)
#pragma unroll
      for (int j = 0; j < 2; ++j) {
        acc[i][j] = __builtin_amdgcn_mfma_f32_16x16x32_bf16(ah[i], bh[j], acc[i][j], 0, 0, 0);
        acc[i][j] = __builtin_amdgcn_mfma_f32_16x16x32_bf16(al[i], bh[j], acc[i][j], 0, 0, 0);
        acc[i][j] = __builtin_amdgcn_mfma_f32_16x16x32_bf16(ah[i], bl[j], acc[i][j], 0, 0, 0);
      }
    __syncthreads();
  }

  // D layout (16x16x32): row = q*4 + r, col = r16
#pragma unroll
  for (int i = 0; i < 4; ++i) {
    int m = (int)m0 + wm + i * 16 + q * 4;
#pragma unroll
    for (int j = 0; j < 2; ++j) {
      int n = (int)n0 + wn + j * 16 + r16;
      if (EPI == 3) {
        u16* dh = (n < 512) ? Ch : Ch2;
        u16* dl = (n < 512) ? Cl : Cl2;
        int nn = n & 511;
#pragma unroll
        for (int r = 0; r < 4; ++r) {
          float v = acc[i][j][r];
          u16 h = f2bf_rn(v);
          dh[(long)(m + r) * 512 + nn] = h;
          dl[(long)(m + r) * 512 + nn] = f2bf_rn(v - bf2f(h));
        }
      } else if (EPI == 4) {
        if (n < 512) {
          float vb = bias[n];
#pragma unroll
          for (int r = 0; r < 4; ++r) {
            float t = acc[i][j][r] + vb;
            t = (t > 20.f) ? t : __logf(1.f + __expf(t));
            u16 h = f2bf_rn(t);
            Ch[(long)(m + r) * 512 + n] = h;
            Cl[(long)(m + r) * 512 + n] = f2bf_rn(t - bf2f(h));
          }
        } else if (n < 544) {
#pragma unroll
          for (int r = 0; r < 4; ++r) C2[(long)(m + r) * 32 + (n - 512)] = acc[i][j][r];
        }
      } else if (EPI == 5) {
#pragma unroll
        for (int r = 0; r < 4; ++r) {
          float v = acc[i][j][r];
          u16 h = f2bf_rn(v);
          Ch[(long)(m + r) * 256 + n] = h;
          Cl[(long)(m + r) * 256 + n] = f2bf_rn(v - bf2f(h));
        }
      } else {  // EPI == 2
        float vb = bias[n];
        int spk = n >> 8, c = n & 255;
        int b = m >> 11, l = m & 2047;
        float4v v;
#pragma unroll
        for (int r = 0; r < 4; ++r) {
          float t = acc[i][j][r] + vb;
          v[r] = t > 0.f ? t : 0.f;
        }
        *(float4v*)&C[(((long)(spk * BATCH + b)) * CIN + c) * L_SEQ + l] = v;
      }
    }
  }
}

// ------ depthwise causal conv(4) + bias + SiLU, banded; xr in hi/lo planes ------
__global__ __launch_bounds__(256) void conv_silu(const u16* __restrict__ xrh,
                                                 const u16* __restrict__ xrl,
                                                 const float* __restrict__ cw,
                                                 const float* __restrict__ cb,
                                                 u16* __restrict__ xch, u16* __restrict__ xcl) {
  int tid = threadIdx.x;
  int d = (tid & 127) * 4;
  int r0 = blockIdx.x * 32 + (tid >> 7) * 16;  // gridDim.x = M_ROWS/32
  float4v wv[4];
#pragma unroll
  for (int e = 0; e < 4; ++e) wv[e] = *(const float4v*)&cw[(d + e) * 4];
  float4v bias4 = *(const float4v*)&cb[d];
  float4v x0 = {0.f, 0.f, 0.f, 0.f}, x1 = x0, x2 = x0, x3;
  if ((r0 & 2047) != 0) {
#pragma unroll
    for (int p = 0; p < 3; ++p) {
      long row = (long)(r0 - 3 + p) * 512 + d;
      ushort4v hh = *(const ushort4v*)&xrh[row];
      ushort4v ll = *(const ushort4v*)&xrl[row];
      float4v xv;
#pragma unroll
      for (int e = 0; e < 4; ++e) xv[e] = bf2f(hh[e]) + bf2f(ll[e]);
      if (p == 0) x0 = xv;
      else if (p == 1) x1 = xv;
      else x2 = xv;
    }
  }
#pragma unroll 4
  for (int t = 0; t < 16; ++t) {
    long row = (long)(r0 + t) * 512 + d;
    ushort4v hh = *(const ushort4v*)&xrh[row];
    ushort4v ll = *(const ushort4v*)&xrl[row];
#pragma unroll
    for (int e = 0; e < 4; ++e) x3[e] = bf2f(hh[e]) + bf2f(ll[e]);
    ushort4v oh, ol;
#pragma unroll
    for (int e = 0; e < 4; ++e) {
      float a = bias4[e] + wv[e][0] * x0[e] + wv[e][1] * x1[e] + wv[e][2] * x2[e] +
                wv[e][3] * x3[e];
      float v = a / (1.f + __expf(-a));
      u16 h = f2bf_rn(v);
      oh[e] = h;
      ol[e] = f2bf_rn(v - bf2f(h));
    }
    *(ushort4v*)&xch[row] = oh;
    *(ushort4v*)&xcl[row] = ol;
    x0 = x1;
    x1 = x2;
    x2 = x3;
  }
}

// ---------------- chunked selective scan: thread per (b,d), 16 states in registers ------------
__global__ __launch_bounds__(256) void scan_pass1(const u16* __restrict__ dh,
                                                  const u16* __restrict__ dl,
                                                  const u16* __restrict__ xch,
                                                  const u16* __restrict__ xcl,
                                                  const float* __restrict__ bc,
                                                  const float* __restrict__ A_log,
                                                  float* __restrict__ P,
                                                  float* __restrict__ Hl) {
  int b = blockIdx.z, c = blockIdx.y;
  int tid = threadIdx.x;
  int d = blockIdx.x * 256 + tid;
  __shared__ float sBC[LC][32];
  const long base = (long)b * L_SEQ + (long)c * LC;
  ((float4v*)sBC)[tid] = ((const float4v*)&bc[base * 32])[tid];
  float Aval[16];
  {
    float4v a[4];
#pragma unroll
    for (int g = 0; g < 4; ++g) a[g] = *(const float4v*)&A_log[d * 16 + g * 4];
#pragma unroll
    for (int s = 0; s < 16; ++s) Aval[s] = -__expf(a[s >> 2][s & 3]);
  }
  __syncthreads();
  float h[16];
#pragma unroll
  for (int s = 0; s < 16; ++s) h[s] = 0.f;
  float sd = 0.f;
#pragma unroll 4
  for (int t = 0; t < LC; ++t) {
    long off = (base + t) * 512 + d;
    float dlv = bf2f(dh[off]) + bf2f(dl[off]);
    float xv = bf2f(xch[off]) + bf2f(xcl[off]);
    float w = dlv * xv;
    sd += dlv;
    float4v Bv[4];
#pragma unroll
    for (int g = 0; g < 4; ++g) Bv[g] = *(const float4v*)&sBC[t][g * 4];
#pragma unroll
    for (int s = 0; s < 16; ++s) {
      float dA = __expf(dlv * Aval[s]);
      h[s] = dA * h[s] + w * Bv[s >> 2][s & 3];
    }
  }
  long idx = (((long)b * NC + c) * 512 + d) * 16;
#pragma unroll
  for (int g = 0; g < 4; ++g) {
    float4v pv, hv;
#pragma unroll
    for (int e = 0; e < 4; ++e) {
      pv[e] = __expf(Aval[g * 4 + e] * sd);
      hv[e] = h[g * 4 + e];
    }
    *(float4v*)&P[idx + g * 4] = pv;
    *(float4v*)&Hl[idx + g * 4] = hv;
  }
}

__global__ __launch_bounds__(256) void scan_combine(const float* __restrict__ P,
                                                    const float* __restrict__ Hl,
                                                    float* __restrict__ H0) {
  int idx = blockIdx.x * 256 + threadIdx.x;  // over B*512*16 = 65536
  int b = idx >> 13;
  int ds = idx & 8191;
  float h = 0.f;
#pragma unroll 8
  for (int c = 0; c < NC; ++c) {
    long off = (((long)b * NC + c) << 13) + ds;
    H0[off] = h;
    h = P[off] * h + Hl[off];
  }
}

__global__ __launch_bounds__(256) void scan_pass2(const u16* __restrict__ dh,
                                                  const u16* __restrict__ dl,
                                                  u16* __restrict__ yh, u16* __restrict__ yl,
                                                  const u16* __restrict__ xch,
                                                  const u16* __restrict__ xcl,
                                                  const float* __restrict__ bc,
                                                  const u16* __restrict__ zh,
                                                  const u16* __restrict__ zl,
                                                  const float* __restrict__ A_log,
                                                  const float* __restrict__ Dp,
                                                  const float* __restrict__ H0) {
  int b = blockIdx.z, c = blockIdx.y;
  int tid = threadIdx.x;
  int d = blockIdx.x * 256 + tid;
  __shared__ float sBC[LC][32];
  const long base = (long)b * L_SEQ + (long)c * LC;
  ((float4v*)sBC)[tid] = ((const float4v*)&bc[base * 32])[tid];
  float Aval[16];
  {
    float4v a[4];
#pragma unroll
    for (int g = 0; g < 4; ++g) a[g] = *(const float4v*)&A_log[d * 16 + g * 4];
#pragma unroll
    for (int s = 0; s < 16; ++s) Aval[s] = -__expf(a[s >> 2][s & 3]);
  }
  float Dval = Dp[d];
  float h[16];
  {
    long hidx = (((long)b * NC + c) * 512 + d) * 16;
#pragma unroll
    for (int g = 0; g < 4; ++g) {
      float4v hv = *(const float4v*)&H0[hidx + g * 4];
#pragma unroll
      for (int e = 0; e < 4; ++e) h[g * 4 + e] = hv[e];
    }
  }
  __syncthreads();
#pragma unroll 4
  for (int t = 0; t < LC; ++t) {
    long off = (base + t) * 512 + d;
    float dlv = bf2f(dh[off]) + bf2f(dl[off]);
    float xv = bf2f(xch[off]) + bf2f(xcl[off]);
    float zv = bf2f(zh[off]) + bf2f(zl[off]);
    float w = dlv * xv;
    float4v Bv[4], Cv[4];
#pragma unroll
    for (int g = 0; g < 4; ++g) {
      Bv[g] = *(const float4v*)&sBC[t][g * 4];
      Cv[g] = *(const float4v*)&sBC[t][16 + g * 4];
    }
    float ya = 0.f, yb = 0.f, yc2 = 0.f, yd = 0.f;
#pragma unroll
    for (int s = 0; s < 4; ++s) {
      float dA = __expf(dlv * Aval[s]);
      h[s] = dA * h[s] + w * Bv[0][s];
      ya += h[s] * Cv[0][s];
    }
#pragma unroll
    for (int s = 4; s < 8; ++s) {
      float dA = __expf(dlv * Aval[s]);
      h[s] = dA * h[s] + w * Bv[1][s - 4];
      yb += h[s] * Cv[1][s - 4];
    }
#pragma unroll
    for (int s = 8; s < 12; ++s) {
      float dA = __expf(dlv * Aval[s]);
      h[s] = dA * h[s] + w * Bv[2][s - 8];
      yc2 += h[s] * Cv[2][s - 8];
    }
#pragma unroll
    for (int s = 12; s < 16; ++s) {
      float dA = __expf(dlv * Aval[s]);
      h[s] = dA * h[s] + w * Bv[3][s - 12];
      yd += h[s] * Cv[3][s - 12];
    }
    float yv = (ya + yb) + (yc2 + yd);
    float yf = (yv + xv * Dval) * (zv / (1.f + __expf(-zv)));
    u16 hh = f2bf_rn(yf);
    yh[off] = hh;
    yl[off] = f2bf_rn(yf - bf2f(hh));
  }
}

extern "C" void kernel_launch(void* const* d_in, const int* in_sizes, int n_in, void* d_out,
                              int out_size, void* d_ws, size_t ws_size, hipStream_t stream) {
  const float* input = (const float*)d_in[0];
  const float* in_proj_w = (const float*)d_in[1];
  const float* conv_w = (const float*)d_in[2];
  const float* conv_b = (const float*)d_in[3];
  const float* x_proj_w = (const float*)d_in[4];
  const float* dt_proj_w = (const float*)d_in[5];
  const float* dt_proj_b = (const float*)d_in[6];
  const float* A_log = (const float*)d_in[7];
  const float* Dp = (const float*)d_in[8];
  const float* out_proj_w = (const float*)d_in[9];
  const float* out_lin_w = (const float*)d_in[10];
  const float* out_lin_b = (const float*)d_in[11];

  char* ws = (char*)d_ws;
  u16* buf_xh = (u16*)(ws);                  // 8.39 MB
  u16* buf_xl = (u16*)(ws + 8388608);        // 8.39 MB (region hosts H0 during scan)
  u16* buf_xrh = (u16*)(ws + 16777216);      // 16.78 MB (P aliases after conv; then yh)
  u16* buf_xrl = (u16*)(ws + 33554432);      // 16.78 MB (Hl aliases; then yl)
  u16* buf_zh = (u16*)(ws + 50331648);       // 16.78 MB
  u16* buf_zl = (u16*)(ws + 67108864);       // 16.78 MB
  u16* buf_xch = (u16*)(ws + 83886080);      // 16 MB
  u16* buf_xcl = (u16*)(ws + 100663296);     // 16 MB
  float* buf_bc = (float*)(ws + 117440512);  // 2 MB (M_ROWS x 32)
  u16* buf_wch = (u16*)(ws + 119537664);     // 0.5 MB
  u16* buf_wcl = (u16*)(ws + 120061952);     // 0.5 MB
  u16* buf_dh = (u16*)(ws + 120586240);      // 16.78 MB delta hi
  u16* buf_dl = (u16*)(ws + 137363456);      // 16.78 MB delta lo
  u16* buf_wd0h = (u16*)(ws + 154140672);    // 576x512 planes
  u16* buf_wd0l = (u16*)(ws + 154796032);
  u16* buf_wd1h = (u16*)(ws + 155451392);
  u16* buf_wd1l = (u16*)(ws + 156106752);
  u16* buf_wth = (u16*)(ws + 156762112);     // 0.5 MB reusable weight scratch
  u16* buf_wtl = (u16*)(ws + 157286400);
  float* buf_P = (float*)(ws + 16777216);    // 16.78 MB (xr planes dead after conv)
  float* buf_Hl = (float*)(ws + 33554432);   // 16.78 MB
  float* buf_H0 = (float*)ws;                // 16.78 MB (x planes dead during scan)
  u16* buf_yh = (u16*)(ws + 16777216);       // over P (dead after combine)
  u16* buf_yl = (u16*)(ws + 33554432);       // over Hl

  build_wd<<<dim3(2, 576), 256, 0, stream>>>(x_proj_w, dt_proj_w, buf_wd0h, buf_wd0l);
  build_wd<<<dim3(2, 576), 256, 0, stream>>>(x_proj_w + 48 * 512, dt_proj_w + 512 * 16, buf_wd1h,
                                             buf_wd1l);
  build_wcomb<<<dim3(2, 512), 256, 0, stream>>>(out_lin_w, out_proj_w + (long)256 * 512, buf_wch,
                                                buf_wcl);
  transpose_in<<<dim3(64, 8, 8), dim3(32, 8), 0, stream>>>(input, buf_xh, buf_xl);

  for (int i = 0; i < 2; ++i) {
    split_pack<<<1024, 256, 0, stream>>>(in_proj_w + (long)i * 1024 * 256, buf_wth, buf_wtl,
                                         1024 * 256);
    gemm_mfma<3, 16><<<2048, 256, 0, stream>>>(buf_xh, buf_xl, 256, buf_wth, buf_wtl, 256,
                                               nullptr, nullptr, buf_xrh, buf_xrl, buf_zh,
                                               buf_zl, nullptr);
    conv_silu<<<512, 256, 0, stream>>>(buf_xrh, buf_xrl, conv_w + i * 512 * 4, conv_b + i * 512,
                                       buf_xch, buf_xcl);
    gemm_mfma<4, 9><<<1152, 256, 0, stream>>>(
        buf_xch, buf_xcl, 512, (i == 0) ? buf_wd0h : buf_wd1h, (i == 0) ? buf_wd0l : buf_wd1l,
        512, nullptr, buf_bc, buf_dh, buf_dl, nullptr, nullptr, dt_proj_b + i * 512);
    scan_pass1<<<dim3(2, NC, 8), 256, 0, stream>>>(buf_dh, buf_dl, buf_xch, buf_xcl, buf_bc,
                                                   A_log + (long)i * 512 * 16, buf_P, buf_Hl);
    scan_combine<<<256, 256, 0, stream>>>(buf_P, buf_Hl, buf_H0);
    scan_pass2<<<dim3(2, NC, 8), 256, 0, stream>>>(buf_dh, buf_dl, buf_yh, buf_yl, buf_xch,
                                                   buf_xcl, buf_bc, buf_zh, buf_zl,
                                                   A_log + (long)i * 512 * 16, Dp + i * 512,
                                                   buf_H0);
    if (i == 0) {
      split_pack<<<512, 256, 0, stream>>>(out_proj_w, buf_wth, buf_wtl, 256 * 512);
      gemm_mfma<5, 4><<<512, 256, 0, stream>>>(buf_yh, buf_yl, 512, buf_wth, buf_wtl, 512,
                                               nullptr, nullptr, buf_xh, buf_xl, nullptr,
                                               nullptr, nullptr);
    } else {
      gemm_mfma<2, 8><<<1024, 256, 0, stream>>>(buf_yh, buf_yl, 512, buf_wch, buf_wcl, 512,
                                                (float*)d_out, nullptr, nullptr, nullptr,
                                                nullptr, nullptr, out_lin_b);
    }
  }
}